// Round 1
// baseline (213.277 us; speedup 1.0000x reference)
//
#include <hip/hip_runtime.h>
#include <math.h>

#define BATCH 512
#define NC 100
#define ENUM 4

// ---------------- router: conv3x3(3->16)+relu -> mean -> fc(16->4) -> softmax -> top1 ----------------
__global__ __launch_bounds__(256) void router_kernel(
    const float* __restrict__ x,       // [B,3,32,32]
    const float* __restrict__ cw,      // [16,3,3,3]
    const float* __restrict__ cb,      // [16]
    const float* __restrict__ fcw,     // [4,16]
    const float* __restrict__ fcb,     // [4]
    float* __restrict__ probs_out,     // [B,4]
    int* __restrict__ sel,             // [B]
    float* __restrict__ pw)            // [B]
{
    __shared__ float xs[3][34][34];
    __shared__ float ws[16][27];
    __shared__ float bs[16];
    __shared__ float red[16][4];
    __shared__ float g[16];
    __shared__ float logits[4];

    const int b = blockIdx.x;
    const int tid = threadIdx.x;

    for (int i = tid; i < 3 * 34 * 34; i += 256) ((float*)xs)[i] = 0.f;
    for (int i = tid; i < 16 * 27; i += 256) ((float*)ws)[i] = cw[i];
    if (tid < 16) bs[tid] = cb[tid];
    __syncthreads();

    const float* xb = x + b * 3072;
    for (int i = tid; i < 3072; i += 256) {
        int c = i >> 10, r = (i >> 5) & 31, cc = i & 31;
        xs[c][r + 1][cc + 1] = xb[i];
    }
    __syncthreads();

    float acc[16];
#pragma unroll
    for (int o = 0; o < 16; ++o) acc[o] = 0.f;

    for (int k = 0; k < 4; ++k) {
        int p = tid + k * 256;
        int y = p >> 5, xx = p & 31;
        float v[27];
#pragma unroll
        for (int c = 0; c < 3; ++c)
#pragma unroll
            for (int ky = 0; ky < 3; ++ky)
#pragma unroll
                for (int kx = 0; kx < 3; ++kx)
                    v[c * 9 + ky * 3 + kx] = xs[c][y + ky][xx + kx];
#pragma unroll
        for (int o = 0; o < 16; ++o) {
            float s = bs[o];
#pragma unroll
            for (int j = 0; j < 27; ++j) s += v[j] * ws[o][j];
            acc[o] += fmaxf(s, 0.f);
        }
    }

    const int wid = tid >> 6;
#pragma unroll
    for (int o = 0; o < 16; ++o) {
        float s = acc[o];
#pragma unroll
        for (int off = 32; off > 0; off >>= 1) s += __shfl_down(s, off);
        if ((tid & 63) == 0) red[o][wid] = s;
    }
    __syncthreads();
    if (tid < 16) g[tid] = (red[tid][0] + red[tid][1] + red[tid][2] + red[tid][3]) * (1.f / 1024.f);
    __syncthreads();
    if (tid < 4) {
        float s = fcb[tid];
#pragma unroll
        for (int o = 0; o < 16; ++o) s += g[o] * fcw[tid * 16 + o];
        logits[tid] = s;
    }
    __syncthreads();
    if (tid == 0) {
        float m = logits[0];
        for (int e = 1; e < 4; ++e) m = fmaxf(m, logits[e]);
        float ex[4], s = 0.f;
        for (int e = 0; e < 4; ++e) { ex[e] = expf(logits[e] - m); s += ex[e]; }
        float inv = 1.f / s;
        int am = 0; float best = ex[0];
        for (int e = 1; e < 4; ++e) { if (ex[e] > best) { best = ex[e]; am = e; } }
        for (int e = 0; e < 4; ++e) probs_out[b * 4 + e] = ex[e] * inv;
        sel[b] = am;
        pw[b] = best * inv;
    }
}

// ---------------- aux loss ----------------
__global__ __launch_bounds__(256) void aux_kernel(const float* __restrict__ probs,
                                                  float* __restrict__ aux_out)
{
    __shared__ float red[256][4];
    const int tid = threadIdx.x;
    float s0 = 0, s1 = 0, s2 = 0, s3 = 0;
    for (int b = tid; b < BATCH; b += 256) {
        s0 += probs[b * 4 + 0]; s1 += probs[b * 4 + 1];
        s2 += probs[b * 4 + 2]; s3 += probs[b * 4 + 3];
    }
    red[tid][0] = s0; red[tid][1] = s1; red[tid][2] = s2; red[tid][3] = s3;
    __syncthreads();
    for (int off = 128; off > 0; off >>= 1) {
        if (tid < off) {
#pragma unroll
            for (int e = 0; e < 4; ++e) red[tid][e] += red[tid + off][e];
        }
        __syncthreads();
    }
    if (tid == 0) {
        float aux = 0;
        for (int e = 0; e < 4; ++e) {
            float mp = red[0][e] * (1.f / BATCH) - 0.25f;
            aux += mp * mp;
        }
        aux_out[0] = aux * 0.25f;
    }
}

// ---------------- expert conv1: conv3x3(3->32)+relu+maxpool2 ----------------
__global__ __launch_bounds__(256) void expert1_kernel(
    const float* __restrict__ x,
    const float* __restrict__ w1,   // [4,32,3,3,3]
    const float* __restrict__ b1,   // [4,32]
    const int* __restrict__ sel,
    float* __restrict__ h1)         // [B,32,16,16]
{
    __shared__ float xs[3][34][34];
    __shared__ float ws[32][27];
    __shared__ float bs[32];
    const int b = blockIdx.x, tid = threadIdx.x;
    const int e = sel[b];

    for (int i = tid; i < 3 * 34 * 34; i += 256) ((float*)xs)[i] = 0.f;
    for (int i = tid; i < 32 * 27; i += 256) ((float*)ws)[i] = w1[e * 864 + i];
    if (tid < 32) bs[tid] = b1[e * 32 + tid];
    __syncthreads();

    const float* xb = x + b * 3072;
    for (int i = tid; i < 3072; i += 256) {
        int c = i >> 10, r = (i >> 5) & 31, cc = i & 31;
        xs[c][r + 1][cc + 1] = xb[i];
    }
    __syncthreads();

    float* out = h1 + b * 8192;
    for (int k = 0; k < 32; ++k) {
        int p = tid + k * 256;          // [oc(32)][py(16)][px(16)]
        int oc = p >> 8;
        int py = (p >> 4) & 15, px = p & 15;
        float m = 0.f;                   // relu >= 0 so 0 is a valid identity
#pragma unroll
        for (int dy = 0; dy < 2; ++dy) {
#pragma unroll
            for (int dx = 0; dx < 2; ++dx) {
                int y = 2 * py + dy, xx = 2 * px + dx;
                float s = bs[oc];
#pragma unroll
                for (int c = 0; c < 3; ++c)
#pragma unroll
                    for (int ky = 0; ky < 3; ++ky)
#pragma unroll
                        for (int kx = 0; kx < 3; ++kx)
                            s += xs[c][y + ky][xx + kx] * ws[oc][c * 9 + ky * 3 + kx];
                m = fmaxf(m, s);
            }
        }
        out[p] = m;
    }
}

// ---------------- expert conv2: conv3x3(32->64)+relu+maxpool2 ----------------
__global__ __launch_bounds__(256) void expert2_kernel(
    const float* __restrict__ h1,   // [B,32,16,16]
    const float* __restrict__ w2,   // [4,64,32,3,3]
    const float* __restrict__ b2,   // [4,64]
    const int* __restrict__ sel,
    float* __restrict__ h2)         // [B,64,8,8]
{
    __shared__ float hs[32][18][18];    // 41.5 KB, halo padded
    const int b = blockIdx.x, tid = threadIdx.x;
    const int e = sel[b];

    for (int i = tid; i < 32 * 18 * 18; i += 256) ((float*)hs)[i] = 0.f;
    __syncthreads();
    const float* hb = h1 + b * 8192;
    for (int i = tid; i < 8192; i += 256) {
        int c = i >> 8, r = (i >> 4) & 15, cc = i & 15;
        hs[c][r + 1][cc + 1] = hb[i];
    }
    __syncthreads();

    const int oc = tid >> 2;        // 0..63
    const int q = tid & 3;          // 0..3 -> pooled row pairs
    const float* wbase = w2 + ((e * 64 + oc) * 32) * 9;
    const float bias = b2[e * 64 + oc];
    float* out = h2 + b * 4096 + oc * 64;

    for (int pr = 2 * q; pr < 2 * q + 2; ++pr) {   // pooled rows (each = 2 conv rows)
        float a0[16], a1[16];
#pragma unroll
        for (int i = 0; i < 16; ++i) { a0[i] = bias; a1[i] = bias; }
        for (int ic = 0; ic < 32; ++ic) {
            const float* wp = wbase + ic * 9;
            float wv[9];
#pragma unroll
            for (int j = 0; j < 9; ++j) wv[j] = wp[j];
#pragma unroll
            for (int ry = 0; ry < 4; ++ry) {
                const float* row = &hs[ic][2 * pr + ry][0];
                float rv[18];
#pragma unroll
                for (int j = 0; j < 18; ++j) rv[j] = row[j];
                if (ry < 3) {
#pragma unroll
                    for (int xx = 0; xx < 16; ++xx)
                        a0[xx] += wv[ry * 3 + 0] * rv[xx] + wv[ry * 3 + 1] * rv[xx + 1] + wv[ry * 3 + 2] * rv[xx + 2];
                }
                if (ry > 0) {
#pragma unroll
                    for (int xx = 0; xx < 16; ++xx)
                        a1[xx] += wv[(ry - 1) * 3 + 0] * rv[xx] + wv[(ry - 1) * 3 + 1] * rv[xx + 1] + wv[(ry - 1) * 3 + 2] * rv[xx + 2];
                }
            }
        }
#pragma unroll
        for (int p = 0; p < 8; ++p) {
            float m = fmaxf(fmaxf(a0[2 * p], a0[2 * p + 1]), fmaxf(a1[2 * p], a1[2 * p + 1]));
            out[pr * 8 + p] = fmaxf(m, 0.f);
        }
    }
}

// ---------------- fc (4096->100) + top1 combine ----------------
__global__ __launch_bounds__(256) void fc_kernel(
    const float* __restrict__ h2,   // [B,4096]
    const float* __restrict__ fw,   // [4,100,4096]
    const float* __restrict__ fb,   // [4,100]
    const int* __restrict__ sel,
    const float* __restrict__ pw,
    float* __restrict__ outp)       // [B,100]
{
    __shared__ float hsm[4096];
    const int b = blockIdx.x, tid = threadIdx.x;
    const int e = sel[b];
    const float p = pw[b];
    const float* hb = h2 + b * 4096;
    for (int i = tid; i < 4096; i += 256) hsm[i] = hb[i];
    __syncthreads();

    const int wid = tid >> 6, lane = tid & 63;
    for (int c = wid; c < NC; c += 4) {
        const float* wrow = fw + (e * NC + c) * 4096;
        float s = 0.f;
#pragma unroll 8
        for (int j = 0; j < 64; ++j) {
            int i = lane + 64 * j;
            s += hsm[i] * wrow[i];
        }
#pragma unroll
        for (int off = 32; off > 0; off >>= 1) s += __shfl_down(s, off);
        if (lane == 0) outp[b * NC + c] = p * (s + fb[e * NC + c]);
    }
}

extern "C" void kernel_launch(void* const* d_in, const int* in_sizes, int n_in,
                              void* d_out, int out_size, void* d_ws, size_t ws_size,
                              hipStream_t stream) {
    const float* x   = (const float*)d_in[0];
    const float* rcw = (const float*)d_in[1];
    const float* rcb = (const float*)d_in[2];
    const float* rfw = (const float*)d_in[3];
    const float* rfb = (const float*)d_in[4];
    const float* ew1 = (const float*)d_in[5];
    const float* eb1 = (const float*)d_in[6];
    const float* ew2 = (const float*)d_in[7];
    const float* eb2 = (const float*)d_in[8];
    const float* efw = (const float*)d_in[9];
    const float* efb = (const float*)d_in[10];
    (void)in_sizes; (void)n_in; (void)out_size; (void)ws_size;

    float* out       = (float*)d_out;
    float* final_out = out;            // [512,100]
    float* probs_out = out + 51200;    // [512,4]
    float* aux_out   = out + 53248;    // [1]

    char* ws = (char*)d_ws;
    int*   sel = (int*)ws;                                   // 512 ints
    float* pw  = (float*)(ws + 2048);                        // 512 floats
    float* h1  = (float*)(ws + 4096);                        // 512*8192 f32 = 16 MB
    float* h2  = (float*)(ws + 4096 + (size_t)512 * 8192 * 4); // 512*4096 f32 = 8 MB

    router_kernel<<<512, 256, 0, stream>>>(x, rcw, rcb, rfw, rfb, probs_out, sel, pw);
    aux_kernel<<<1, 256, 0, stream>>>(probs_out, aux_out);
    expert1_kernel<<<512, 256, 0, stream>>>(x, ew1, eb1, sel, h1);
    expert2_kernel<<<512, 256, 0, stream>>>(h1, ew2, eb2, sel, h2);
    fc_kernel<<<512, 256, 0, stream>>>(h2, efw, efb, sel, pw, final_out);
}

// Round 2
// 193.157 us; speedup vs baseline: 1.1042x; 1.1042x over previous
//
#include <hip/hip_runtime.h>
#include <hip/hip_bf16.h>
#include <math.h>

#define BATCH 512
#define NC 100

typedef __attribute__((ext_vector_type(8))) short bf16x8;
typedef __attribute__((ext_vector_type(4))) float f32x4;

// ---------------- router: conv3x3(3->16)+relu -> mean -> fc(16->4) -> softmax -> top1 ----------------
__global__ __launch_bounds__(256) void router_kernel(
    const float* __restrict__ x,       // [B,3,32,32]
    const float* __restrict__ cw,      // [16,3,3,3]
    const float* __restrict__ cb,      // [16]
    const float* __restrict__ fcw,     // [4,16]
    const float* __restrict__ fcb,     // [4]
    float* __restrict__ probs_out,     // [B,4]
    int* __restrict__ sel,             // [B]
    float* __restrict__ pw)            // [B]
{
    __shared__ float xs[3][34][34];
    __shared__ float ws[16][27];
    __shared__ float bs[16];
    __shared__ float red[16][4];
    __shared__ float g[16];
    __shared__ float logits[4];

    const int b = blockIdx.x;
    const int tid = threadIdx.x;

    for (int i = tid; i < 3 * 34 * 34; i += 256) ((float*)xs)[i] = 0.f;
    for (int i = tid; i < 16 * 27; i += 256) ((float*)ws)[i] = cw[i];
    if (tid < 16) bs[tid] = cb[tid];
    __syncthreads();

    const float* xb = x + b * 3072;
    for (int i = tid; i < 3072; i += 256) {
        int c = i >> 10, r = (i >> 5) & 31, cc = i & 31;
        xs[c][r + 1][cc + 1] = xb[i];
    }
    __syncthreads();

    float acc[16];
#pragma unroll
    for (int o = 0; o < 16; ++o) acc[o] = 0.f;

    for (int k = 0; k < 4; ++k) {
        int p = tid + k * 256;
        int y = p >> 5, xx = p & 31;
        float v[27];
#pragma unroll
        for (int c = 0; c < 3; ++c)
#pragma unroll
            for (int ky = 0; ky < 3; ++ky)
#pragma unroll
                for (int kx = 0; kx < 3; ++kx)
                    v[c * 9 + ky * 3 + kx] = xs[c][y + ky][xx + kx];
#pragma unroll
        for (int o = 0; o < 16; ++o) {
            float s = bs[o];
#pragma unroll
            for (int j = 0; j < 27; ++j) s += v[j] * ws[o][j];
            acc[o] += fmaxf(s, 0.f);
        }
    }

    const int wid = tid >> 6;
#pragma unroll
    for (int o = 0; o < 16; ++o) {
        float s = acc[o];
#pragma unroll
        for (int off = 32; off > 0; off >>= 1) s += __shfl_down(s, off);
        if ((tid & 63) == 0) red[o][wid] = s;
    }
    __syncthreads();
    if (tid < 16) g[tid] = (red[tid][0] + red[tid][1] + red[tid][2] + red[tid][3]) * (1.f / 1024.f);
    __syncthreads();
    if (tid < 4) {
        float s = fcb[tid];
#pragma unroll
        for (int o = 0; o < 16; ++o) s += g[o] * fcw[tid * 16 + o];
        logits[tid] = s;
    }
    __syncthreads();
    if (tid == 0) {
        float m = logits[0];
        for (int e = 1; e < 4; ++e) m = fmaxf(m, logits[e]);
        float ex[4], s = 0.f;
        for (int e = 0; e < 4; ++e) { ex[e] = expf(logits[e] - m); s += ex[e]; }
        float inv = 1.f / s;
        int am = 0; float best = ex[0];
        for (int e = 1; e < 4; ++e) { if (ex[e] > best) { best = ex[e]; am = e; } }
        for (int e = 0; e < 4; ++e) probs_out[b * 4 + e] = ex[e] * inv;
        sel[b] = am;
        pw[b] = best * inv;
    }
}

// ---------------- aux loss ----------------
__global__ __launch_bounds__(256) void aux_kernel(const float* __restrict__ probs,
                                                  float* __restrict__ aux_out)
{
    __shared__ float red[256][4];
    const int tid = threadIdx.x;
    float s0 = 0, s1 = 0, s2 = 0, s3 = 0;
    for (int b = tid; b < BATCH; b += 256) {
        s0 += probs[b * 4 + 0]; s1 += probs[b * 4 + 1];
        s2 += probs[b * 4 + 2]; s3 += probs[b * 4 + 3];
    }
    red[tid][0] = s0; red[tid][1] = s1; red[tid][2] = s2; red[tid][3] = s3;
    __syncthreads();
    for (int off = 128; off > 0; off >>= 1) {
        if (tid < off) {
#pragma unroll
            for (int e = 0; e < 4; ++e) red[tid][e] += red[tid + off][e];
        }
        __syncthreads();
    }
    if (tid == 0) {
        float aux = 0;
        for (int e = 0; e < 4; ++e) {
            float mp = red[0][e] * (1.f / BATCH) - 0.25f;
            aux += mp * mp;
        }
        aux_out[0] = aux * 0.25f;
    }
}

// ---------------- scan: per-expert compaction (ids grouped by expert, offsets) ----------------
__global__ __launch_bounds__(512) void scan_kernel(const int* __restrict__ sel,
                                                   int* __restrict__ ids,
                                                   int* __restrict__ offs)
{
    __shared__ int ssel[512];
    __shared__ int cnt[4];
    __shared__ int soff[5];
    const int tid = threadIdx.x;
    ssel[tid] = sel[tid];
    if (tid < 4) cnt[tid] = 0;
    __syncthreads();
    const int e = ssel[tid];
    int r = 0;
    for (int j = 0; j < 512; ++j) {
        r += (j < tid && ssel[j] == e) ? 1 : 0;
    }
    atomicAdd(&cnt[e], 1);
    __syncthreads();
    if (tid == 0) {
        int o = 0;
        for (int k = 0; k < 4; ++k) { soff[k] = o; o += cnt[k]; }
        soff[4] = o;
        for (int k = 0; k < 5; ++k) offs[k] = soff[k];
    }
    __syncthreads();
    ids[soff[e] + r] = tid;
}

// ---------------- convert fc weights to bf16 ----------------
__global__ __launch_bounds__(256) void cvt_fw_kernel(const float* __restrict__ fw,
                                                     __hip_bfloat16* __restrict__ fwb)
{
    const int i = (blockIdx.x * 256 + threadIdx.x) * 4;   // n = 1,638,400 divisible by 4
    float4 v = *(const float4*)(fw + i);
    __hip_bfloat16 o[4];
    o[0] = __float2bfloat16(v.x); o[1] = __float2bfloat16(v.y);
    o[2] = __float2bfloat16(v.z); o[3] = __float2bfloat16(v.w);
    *(uint2*)(fwb + i) = *(uint2*)o;
}

// ---------------- expert conv1: conv3x3(3->32)+relu+maxpool2 ----------------
__global__ __launch_bounds__(256) void expert1_kernel(
    const float* __restrict__ x,
    const float* __restrict__ w1,   // [4,32,3,3,3]
    const float* __restrict__ b1,   // [4,32]
    const int* __restrict__ sel,
    float* __restrict__ h1)         // [B,32,16,16]
{
    __shared__ float xs[3][34][34];
    __shared__ float ws[32][27];
    __shared__ float bs[32];
    const int b = blockIdx.x, tid = threadIdx.x;
    const int e = sel[b];

    for (int i = tid; i < 3 * 34 * 34; i += 256) ((float*)xs)[i] = 0.f;
    for (int i = tid; i < 32 * 27; i += 256) ((float*)ws)[i] = w1[e * 864 + i];
    if (tid < 32) bs[tid] = b1[e * 32 + tid];
    __syncthreads();

    const float* xb = x + b * 3072;
    for (int i = tid; i < 3072; i += 256) {
        int c = i >> 10, r = (i >> 5) & 31, cc = i & 31;
        xs[c][r + 1][cc + 1] = xb[i];
    }
    __syncthreads();

    float* out = h1 + b * 8192;
    for (int k = 0; k < 32; ++k) {
        int p = tid + k * 256;          // [oc(32)][py(16)][px(16)]
        int oc = p >> 8;
        int py = (p >> 4) & 15, px = p & 15;
        float m = 0.f;                   // relu >= 0 so 0 is a valid identity
#pragma unroll
        for (int dy = 0; dy < 2; ++dy) {
#pragma unroll
            for (int dx = 0; dx < 2; ++dx) {
                int y = 2 * py + dy, xx = 2 * px + dx;
                float s = bs[oc];
#pragma unroll
                for (int c = 0; c < 3; ++c)
#pragma unroll
                    for (int ky = 0; ky < 3; ++ky)
#pragma unroll
                        for (int kx = 0; kx < 3; ++kx)
                            s += xs[c][y + ky][xx + kx] * ws[oc][c * 9 + ky * 3 + kx];
                m = fmaxf(m, s);
            }
        }
        out[p] = m;
    }
}

// ---------------- expert conv2: conv3x3(32->64)+relu+maxpool2, bf16 output ----------------
__global__ __launch_bounds__(512) void expert2_kernel(
    const float* __restrict__ h1,   // [B,32,16,16]
    const float* __restrict__ w2,   // [4,64,32,3,3]
    const float* __restrict__ b2,   // [4,64]
    const int* __restrict__ sel,
    __hip_bfloat16* __restrict__ h2b) // [B,4096] bf16
{
    __shared__ float hs[32][18][18];    // 41.5 KB, halo padded
    const int b = blockIdx.x, tid = threadIdx.x;
    const int e = sel[b];

    for (int i = tid; i < 32 * 18 * 18; i += 512) ((float*)hs)[i] = 0.f;
    __syncthreads();
    const float* hb = h1 + b * 8192;
    for (int i = tid; i < 8192; i += 512) {
        int c = i >> 8, r = (i >> 4) & 15, cc = i & 15;
        hs[c][r + 1][cc + 1] = hb[i];
    }
    __syncthreads();

    const int oc = tid >> 3;        // 0..63
    const int pr = tid & 7;         // pooled row 0..7
    const float* wbase = w2 + ((e * 64 + oc) * 32) * 9;
    const float bias = b2[e * 64 + oc];

    float a0[16], a1[16];
#pragma unroll
    for (int i = 0; i < 16; ++i) { a0[i] = 0.f; a1[i] = 0.f; }

    for (int ic = 0; ic < 32; ++ic) {
        const float* wp = wbase + ic * 9;
        float wv[9];
#pragma unroll
        for (int j = 0; j < 9; ++j) wv[j] = wp[j];
#pragma unroll
        for (int ry = 0; ry < 4; ++ry) {
            const float* row = &hs[ic][2 * pr + ry][0];
            float rv[18];
#pragma unroll
            for (int j = 0; j < 18; ++j) rv[j] = row[j];
            if (ry < 3) {
#pragma unroll
                for (int xx = 0; xx < 16; ++xx)
                    a0[xx] += wv[ry * 3 + 0] * rv[xx] + wv[ry * 3 + 1] * rv[xx + 1] + wv[ry * 3 + 2] * rv[xx + 2];
            }
            if (ry > 0) {
#pragma unroll
                for (int xx = 0; xx < 16; ++xx)
                    a1[xx] += wv[(ry - 1) * 3 + 0] * rv[xx] + wv[(ry - 1) * 3 + 1] * rv[xx + 1] + wv[(ry - 1) * 3 + 2] * rv[xx + 2];
            }
        }
    }
    __hip_bfloat16 ob[8];
#pragma unroll
    for (int p = 0; p < 8; ++p) {
        float m = fmaxf(fmaxf(a0[2 * p], a0[2 * p + 1]), fmaxf(a1[2 * p], a1[2 * p + 1]));
        ob[p] = __float2bfloat16(fmaxf(m + bias, 0.f));
    }
    *(uint4*)(h2b + b * 4096 + oc * 64 + pr * 8) = *(uint4*)ob;
}

// ---------------- fc: expert-grouped bf16 MFMA GEMM + top1 combine ----------------
// grid: (sample tile 0..15, class tile 0..3, expert 0..3); block 256 = 4 waves (2m x 2n)
__global__ __launch_bounds__(256) void fc_mfma_kernel(
    const __hip_bfloat16* __restrict__ h2b,   // [512,4096]
    const __hip_bfloat16* __restrict__ fwb,   // [4,100,4096]
    const float* __restrict__ fb,             // [4,100]
    const int* __restrict__ ids,              // [512] grouped by expert
    const int* __restrict__ offs,             // [5]
    const float* __restrict__ pw,             // [512]
    float* __restrict__ outp)                 // [512,100]
{
    const int e = blockIdx.z, ct = blockIdx.y, st = blockIdx.x;
    const int off = offs[e], cnt = offs[e + 1] - off;
    if (st * 32 >= cnt) return;

    const int tid = threadIdx.x;
    const int w = tid >> 6, lane = tid & 63;
    const int m0 = st * 32 + (w >> 1) * 16;   // slot base (within expert)
    const int n0 = ct * 32 + (w & 1) * 16;    // class base
    const int lr = lane & 15, kb = lane >> 4;

    const int slot = m0 + lr;
    const int sidx = ids[off + (slot < cnt ? slot : cnt - 1)];
    const int cls = n0 + lr;
    const int clsc = cls < NC ? cls : NC - 1;

    const bf16x8* ap = (const bf16x8*)(h2b + (size_t)sidx * 4096 + kb * 8);
    const bf16x8* bp = (const bf16x8*)(fwb + (size_t)(e * NC + clsc) * 4096 + kb * 8);
    f32x4 acc = {0.f, 0.f, 0.f, 0.f};
#pragma unroll 4
    for (int k = 0; k < 128; ++k) {
        bf16x8 a = ap[k * 4];     // stride 32 bf16 per k-step
        bf16x8 bv = bp[k * 4];
        acc = __builtin_amdgcn_mfma_f32_16x16x32_bf16(a, bv, acc, 0, 0, 0);
    }
    // C/D layout: col = lane&15 (n), row = (lane>>4)*4 + j (m)
    const int ccol = n0 + lr;
    if (ccol < NC) {
        const float bias = fb[e * NC + ccol];
#pragma unroll
        for (int j = 0; j < 4; ++j) {
            const int m = m0 + kb * 4 + j;
            if (m < cnt) {
                const int sid = ids[off + m];
                outp[sid * NC + ccol] = pw[sid] * (acc[j] + bias);
            }
        }
    }
}

extern "C" void kernel_launch(void* const* d_in, const int* in_sizes, int n_in,
                              void* d_out, int out_size, void* d_ws, size_t ws_size,
                              hipStream_t stream) {
    const float* x   = (const float*)d_in[0];
    const float* rcw = (const float*)d_in[1];
    const float* rcb = (const float*)d_in[2];
    const float* rfw = (const float*)d_in[3];
    const float* rfb = (const float*)d_in[4];
    const float* ew1 = (const float*)d_in[5];
    const float* eb1 = (const float*)d_in[6];
    const float* ew2 = (const float*)d_in[7];
    const float* eb2 = (const float*)d_in[8];
    const float* efw = (const float*)d_in[9];
    const float* efb = (const float*)d_in[10];
    (void)in_sizes; (void)n_in; (void)out_size; (void)ws_size;

    float* out       = (float*)d_out;
    float* final_out = out;            // [512,100]
    float* probs_out = out + 51200;    // [512,4]
    float* aux_out   = out + 53248;    // [1]

    char* ws = (char*)d_ws;
    int*   sel  = (int*)ws;                                  // 512 ints
    float* pw   = (float*)(ws + 2048);                       // 512 f32
    int*   ids  = (int*)(ws + 4096);                         // 512 ints
    int*   offs = (int*)(ws + 6144);                         // 8 ints
    float* h1   = (float*)(ws + 8192);                       // 512*8192 f32 = 16 MB
    __hip_bfloat16* h2b = (__hip_bfloat16*)(ws + 8192 + (size_t)512 * 8192 * 4);          // 4 MB
    __hip_bfloat16* fwb = (__hip_bfloat16*)(ws + 8192 + (size_t)512 * 8192 * 4
                                               + (size_t)512 * 4096 * 2);                 // 3.28 MB

    cvt_fw_kernel<<<1600, 256, 0, stream>>>(efw, fwb);
    router_kernel<<<512, 256, 0, stream>>>(x, rcw, rcb, rfw, rfb, probs_out, sel, pw);
    aux_kernel<<<1, 256, 0, stream>>>(probs_out, aux_out);
    scan_kernel<<<1, 512, 0, stream>>>(sel, ids, offs);
    expert1_kernel<<<512, 256, 0, stream>>>(x, ew1, eb1, sel, h1);
    expert2_kernel<<<512, 512, 0, stream>>>(h1, ew2, eb2, sel, h2b);
    fc_mfma_kernel<<<dim3(16, 4, 4), 256, 0, stream>>>(h2b, fwb, efb, ids, offs, pw, final_out);
}

// Round 3
// 162.869 us; speedup vs baseline: 1.3095x; 1.1860x over previous
//
#include <hip/hip_runtime.h>
#include <hip/hip_bf16.h>
#include <math.h>

#define BATCH 512
#define NC 100

typedef __attribute__((ext_vector_type(8))) short bf16x8;
typedef __attribute__((ext_vector_type(4))) float f32x4;

__device__ inline ushort f2bf(float f) {
    __hip_bfloat16 h = __float2bfloat16(f);
    return *reinterpret_cast<ushort*>(&h);
}

// ---------------- router: conv3x3(3->16)+relu -> mean -> fc(16->4) -> softmax -> top1 ----------------
__global__ __launch_bounds__(256) void router_kernel(
    const float* __restrict__ x,       // [B,3,32,32]
    const float* __restrict__ cw,      // [16,3,3,3]
    const float* __restrict__ cb,      // [16]
    const float* __restrict__ fcw,     // [4,16]
    const float* __restrict__ fcb,     // [4]
    float* __restrict__ probs_out,     // [B,4]
    int* __restrict__ sel,             // [B]
    float* __restrict__ pw)            // [B]
{
    __shared__ float xs[3][34][34];
    __shared__ float ws[16][27];
    __shared__ float bs[16];
    __shared__ float red[16][4];
    __shared__ float g[16];
    __shared__ float logits[4];

    const int b = blockIdx.x;
    const int tid = threadIdx.x;

    for (int i = tid; i < 3 * 34 * 34; i += 256) ((float*)xs)[i] = 0.f;
    for (int i = tid; i < 16 * 27; i += 256) ((float*)ws)[i] = cw[i];
    if (tid < 16) bs[tid] = cb[tid];
    __syncthreads();

    const float* xb = x + b * 3072;
    for (int i = tid; i < 3072; i += 256) {
        int c = i >> 10, r = (i >> 5) & 31, cc = i & 31;
        xs[c][r + 1][cc + 1] = xb[i];
    }
    __syncthreads();

    float acc[16];
#pragma unroll
    for (int o = 0; o < 16; ++o) acc[o] = 0.f;

    for (int k = 0; k < 4; ++k) {
        int p = tid + k * 256;
        int y = p >> 5, xx = p & 31;
        float v[27];
#pragma unroll
        for (int c = 0; c < 3; ++c)
#pragma unroll
            for (int ky = 0; ky < 3; ++ky)
#pragma unroll
                for (int kx = 0; kx < 3; ++kx)
                    v[c * 9 + ky * 3 + kx] = xs[c][y + ky][xx + kx];
#pragma unroll
        for (int o = 0; o < 16; ++o) {
            float s = bs[o];
#pragma unroll
            for (int j = 0; j < 27; ++j) s += v[j] * ws[o][j];
            acc[o] += fmaxf(s, 0.f);
        }
    }

    const int wid = tid >> 6;
#pragma unroll
    for (int o = 0; o < 16; ++o) {
        float s = acc[o];
#pragma unroll
        for (int off = 32; off > 0; off >>= 1) s += __shfl_down(s, off);
        if ((tid & 63) == 0) red[o][wid] = s;
    }
    __syncthreads();
    if (tid < 16) g[tid] = (red[tid][0] + red[tid][1] + red[tid][2] + red[tid][3]) * (1.f / 1024.f);
    __syncthreads();
    if (tid < 4) {
        float s = fcb[tid];
#pragma unroll
        for (int o = 0; o < 16; ++o) s += g[o] * fcw[tid * 16 + o];
        logits[tid] = s;
    }
    __syncthreads();
    if (tid == 0) {
        float m = logits[0];
        for (int e = 1; e < 4; ++e) m = fmaxf(m, logits[e]);
        float ex[4], s = 0.f;
        for (int e = 0; e < 4; ++e) { ex[e] = expf(logits[e] - m); s += ex[e]; }
        float inv = 1.f / s;
        int am = 0; float best = ex[0];
        for (int e = 1; e < 4; ++e) { if (ex[e] > best) { best = ex[e]; am = e; } }
        for (int e = 0; e < 4; ++e) probs_out[b * 4 + e] = ex[e] * inv;
        sel[b] = am;
        pw[b] = best * inv;
    }
}

// ---------------- aux loss ----------------
__global__ __launch_bounds__(256) void aux_kernel(const float* __restrict__ probs,
                                                  float* __restrict__ aux_out)
{
    __shared__ float red[256][4];
    const int tid = threadIdx.x;
    float s0 = 0, s1 = 0, s2 = 0, s3 = 0;
    for (int b = tid; b < BATCH; b += 256) {
        s0 += probs[b * 4 + 0]; s1 += probs[b * 4 + 1];
        s2 += probs[b * 4 + 2]; s3 += probs[b * 4 + 3];
    }
    red[tid][0] = s0; red[tid][1] = s1; red[tid][2] = s2; red[tid][3] = s3;
    __syncthreads();
    for (int off = 128; off > 0; off >>= 1) {
        if (tid < off) {
#pragma unroll
            for (int e = 0; e < 4; ++e) red[tid][e] += red[tid + off][e];
        }
        __syncthreads();
    }
    if (tid == 0) {
        float aux = 0;
        for (int e = 0; e < 4; ++e) {
            float mp = red[0][e] * (1.f / BATCH) - 0.25f;
            aux += mp * mp;
        }
        aux_out[0] = aux * 0.25f;
    }
}

// ---------------- scan: per-expert compaction ----------------
__global__ __launch_bounds__(512) void scan_kernel(const int* __restrict__ sel,
                                                   int* __restrict__ ids,
                                                   int* __restrict__ offs)
{
    __shared__ int ssel[512];
    __shared__ int cnt[4];
    __shared__ int soff[5];
    const int tid = threadIdx.x;
    ssel[tid] = sel[tid];
    if (tid < 4) cnt[tid] = 0;
    __syncthreads();
    const int e = ssel[tid];
    int r = 0;
    for (int j = 0; j < 512; ++j) {
        r += (j < tid && ssel[j] == e) ? 1 : 0;
    }
    atomicAdd(&cnt[e], 1);
    __syncthreads();
    if (tid == 0) {
        int o = 0;
        for (int k = 0; k < 4; ++k) { soff[k] = o; o += cnt[k]; }
        soff[4] = o;
        for (int k = 0; k < 5; ++k) offs[k] = soff[k];
    }
    __syncthreads();
    ids[soff[e] + r] = tid;
}

// ---------------- convert fc weights to bf16 ----------------
__global__ __launch_bounds__(256) void cvt_fw_kernel(const float* __restrict__ fw,
                                                     ushort* __restrict__ fwb)
{
    const int i = (blockIdx.x * 256 + threadIdx.x) * 4;   // 1,638,400 divisible by 4
    float4 v = *(const float4*)(fw + i);
    ushort o[4];
    o[0] = f2bf(v.x); o[1] = f2bf(v.y); o[2] = f2bf(v.z); o[3] = f2bf(v.w);
    *(uint2*)(fwb + i) = *(uint2*)o;
}

// ---------------- convert conv2 weights: [4,64,32,3,3] f32 -> [4,9,64,32] bf16 ----------------
__global__ __launch_bounds__(256) void cvt_w2_kernel(const float* __restrict__ w2,
                                                     ushort* __restrict__ w2t)
{
    const int i = blockIdx.x * 256 + threadIdx.x;   // 288 blocks * 256 = 73728 exactly
    const int ic = i & 31;
    const int oc = (i >> 5) & 63;
    const int et = i >> 11;            // 0..35
    const int e = et / 9, t = et % 9;
    const float v = w2[((e * 64 + oc) * 32 + ic) * 9 + t];
    w2t[i] = f2bf(v);
}

// ---------------- expert conv1: conv3x3(3->32)+relu+maxpool2 -> h1b [b][16][16][32] bf16 ----------------
__global__ __launch_bounds__(256) void expert1_kernel(
    const float* __restrict__ x,
    const float* __restrict__ w1,   // [4,32,3,3,3]
    const float* __restrict__ b1,   // [4,32]
    const int* __restrict__ sel,
    uint* __restrict__ h1b)         // [B][16][16][32] bf16, as u32 words
{
    __shared__ float xs[3][34][34];
    __shared__ float ws[32][27];
    __shared__ float bs[32];
    __shared__ __align__(16) ushort outs[8192];   // [py][px][oc]
    const int b = blockIdx.x, tid = threadIdx.x;
    const int e = sel[b];

    for (int i = tid; i < 3 * 34 * 34; i += 256) ((float*)xs)[i] = 0.f;
    for (int i = tid; i < 32 * 27; i += 256) ((float*)ws)[i] = w1[e * 864 + i];
    if (tid < 32) bs[tid] = b1[e * 32 + tid];
    __syncthreads();

    const float* xb = x + b * 3072;
    for (int i = tid; i < 3072; i += 256) {
        int c = i >> 10, r = (i >> 5) & 31, cc = i & 31;
        xs[c][r + 1][cc + 1] = xb[i];
    }
    __syncthreads();

    const int oc = tid & 31;
    const float bias = bs[oc];
    for (int k = 0; k < 32; ++k) {
        const int px = ((tid >> 5) & 7) | ((k & 1) << 3);
        const int py = k >> 1;
        float s00 = 0.f, s01 = 0.f, s10 = 0.f, s11 = 0.f;
#pragma unroll
        for (int c = 0; c < 3; ++c) {
            float rv[4][4];
#pragma unroll
            for (int yy = 0; yy < 4; ++yy)
#pragma unroll
                for (int xx = 0; xx < 4; ++xx)
                    rv[yy][xx] = xs[c][2 * py + yy][2 * px + xx];
#pragma unroll
            for (int ky = 0; ky < 3; ++ky)
#pragma unroll
                for (int kx = 0; kx < 3; ++kx) {
                    const float w = ws[oc][c * 9 + ky * 3 + kx];
                    s00 += rv[ky][kx] * w;
                    s01 += rv[ky][kx + 1] * w;
                    s10 += rv[ky + 1][kx] * w;
                    s11 += rv[ky + 1][kx + 1] * w;
                }
        }
        float v = fmaxf(fmaxf(fmaxf(s00, s01), fmaxf(s10, s11)) + bias, 0.f);
        outs[(py * 16 + px) * 32 + oc] = f2bf(v);
    }
    __syncthreads();
    const uint* o32 = (const uint*)outs;
    uint* dst = h1b + (size_t)b * 4096;
    for (int i = tid; i < 4096; i += 256) dst[i] = o32[i];
}

// ---------------- expert conv2 via MFMA: 9 tap-GEMMs, pooled in-register ----------------
__global__ __launch_bounds__(256) void expert2_mfma_kernel(
    const uint* __restrict__ h1b,    // [B][16][16][32] bf16 (u32 words)
    const ushort* __restrict__ w2t,  // [4][9][64][32] bf16
    const float* __restrict__ b2,    // [4,64]
    const int* __restrict__ sel,
    uint* __restrict__ h2b)          // [B][4096] bf16 (u32 words): oc*64+py*8+px
{
    __shared__ __align__(16) ushort A_s[18 * 18 * 32];   // [y][x][ic] halo-padded, 20.7 KB
    __shared__ __align__(16) ushort W_s[9 * 64 * 32];    // [tap][oc][ic], 36.9 KB
    const int b = blockIdx.x, tid = threadIdx.x;
    const int e = sel[b];

    // halo zeros: 1088 u32 words
    uint* A32 = (uint*)A_s;
    for (int i = tid; i < 1088; i += 256) {
        int y, xx, w;
        if (i < 576) { y = (i >= 288) ? 17 : 0; int r2 = i % 288; xx = r2 >> 4; w = r2 & 15; }
        else { int j = i - 576; y = 1 + (j >> 5); xx = ((j >> 4) & 1) ? 17 : 0; w = j & 15; }
        A32[(y * 18 + xx) * 16 + w] = 0u;
    }
    // interior: 4096 u32 words
    const uint* hb = h1b + (size_t)b * 4096;
    for (int i = tid; i < 4096; i += 256) {
        int py = i >> 8, px = (i >> 4) & 15, w = i & 15;
        A32[((py + 1) * 18 + (px + 1)) * 16 + w] = hb[i];
    }
    // weights: 9216 u32 words
    uint* W32 = (uint*)W_s;
    const uint* wg = (const uint*)(w2t + (size_t)e * 18432);
    for (int i = tid; i < 9216; i += 256) W32[i] = wg[i];
    __syncthreads();

    const int wv = tid >> 6, lane = tid & 63;
    const int lr = lane & 15, kb = lane >> 4;

    f32x4 acc[4][4];
#pragma unroll
    for (int m = 0; m < 4; ++m)
#pragma unroll
        for (int n = 0; n < 4; ++n)
            acc[m][n] = (f32x4){0.f, 0.f, 0.f, 0.f};

#pragma unroll
    for (int t = 0; t < 9; ++t) {
        const int ky = t / 3, kx = t % 3;
        bf16x8 af[4], bfr[4];
#pragma unroll
        for (int m = 0; m < 4; ++m) {
            const int y = wv * 4 + m;
            af[m] = *(const bf16x8*)(A_s + ((y + ky) * 18 + (lr + kx)) * 32 + kb * 8);
        }
#pragma unroll
        for (int n = 0; n < 4; ++n)
            bfr[n] = *(const bf16x8*)(W_s + (t * 64 + n * 16 + lr) * 32 + kb * 8);
#pragma unroll
        for (int m = 0; m < 4; ++m)
#pragma unroll
            for (int n = 0; n < 4; ++n)
                acc[m][n] = __builtin_amdgcn_mfma_f32_16x16x32_bf16(af[m], bfr[n], acc[m][n], 0, 0, 0);
    }

    // epilogue: pool 2x2 in-register, +bias, relu, pack 2 bf16 -> u32
    const float bias = b2[e * 64 + lr];   // lane's oc = n*16+lr; bias per n below
#pragma unroll
    for (int q = 0; q < 2; ++q) {
        const int py = wv * 2 + q;
#pragma unroll
        for (int n = 0; n < 4; ++n) {
            const int oc = n * 16 + lr;
            const float bn = (n == 0) ? bias : b2[e * 64 + oc];
            const f32x4 ca = acc[2 * q][n];
            const f32x4 cb = acc[2 * q + 1][n];
            float p0 = fmaxf(fmaxf(ca[0], ca[1]), fmaxf(cb[0], cb[1]));
            float p1 = fmaxf(fmaxf(ca[2], ca[3]), fmaxf(cb[2], cb[3]));
            float r0 = fmaxf(p0 + bn, 0.f);
            float r1 = fmaxf(p1 + bn, 0.f);
            uint pk = (uint)f2bf(r0) | ((uint)f2bf(r1) << 16);
            h2b[(size_t)b * 2048 + oc * 32 + py * 4 + kb] = pk;
        }
    }
}

// ---------------- fc: per-block 32 samples x 112 classes, K-chunked LDS, bf16 MFMA ----------------
// grid: (st 0..15, e 0..3); block 256 = 4 waves; wave w: N-frags {w, w+4(if<7)}
__global__ __launch_bounds__(256) void fc_mfma_kernel(
    const ushort* __restrict__ h2b,   // [512,4096] bf16
    const ushort* __restrict__ fwb,   // [4,100,4096] bf16
    const float* __restrict__ fb,     // [4,100]
    const int* __restrict__ ids,      // [512] grouped by expert
    const int* __restrict__ offs,     // [5]
    const float* __restrict__ pw,     // [512]
    float* __restrict__ outp)         // [512,100]
{
    const int e = blockIdx.y, st = blockIdx.x;
    const int off = offs[e], cnt = offs[e + 1] - off;
    if (st * 32 >= cnt) return;

    __shared__ __align__(16) uint As[8192];   // 32 rows x 256 words (512 bf16), XOR-swizzled chunks
    __shared__ int sids[32];
    __shared__ float spw[32];
    const int tid = threadIdx.x;
    if (tid < 32) {
        int slot = st * 32 + tid;
        int s = ids[off + (slot < cnt ? slot : cnt - 1)];
        sids[tid] = s;
        spw[tid] = pw[s];
    }
    __syncthreads();

    const int wv = tid >> 6, lane = tid & 63;
    const int lr = lane & 15, kb = lane >> 4;
    const int row = tid >> 3;       // staging row 0..31
    const int seg = tid & 7;        // staging segment 0..7
    const uint4* gsrc = (const uint4*)(h2b + (size_t)sids[row] * 4096);
    const int swzr = (row & 7) << 2;

    const int c0 = wv * 16 + lr;
    const int c1 = c0 + 64;
    const bool has2 = (wv < 3);
    const int cc0 = c0 < NC ? c0 : NC - 1;
    const int cc1 = c1 < NC ? c1 : NC - 1;
    const ushort* bsrc0 = fwb + (size_t)(e * NC + cc0) * 4096;
    const ushort* bsrc1 = fwb + (size_t)(e * NC + cc1) * 4096;

    f32x4 a00 = {0,0,0,0}, a10 = {0,0,0,0}, a01 = {0,0,0,0}, a11 = {0,0,0,0};
    const int rswz = (lr & 7) << 2;

    for (int c = 0; c < 8; ++c) {
        // stage chunk c: 32 KB
#pragma unroll
        for (int j = 0; j < 8; ++j) {
            uint4 v = gsrc[c * 64 + seg * 8 + j];
            int cw = ((seg * 32 + j * 4) ^ swzr);
            *(uint4*)(As + row * 256 + cw) = v;
        }
        __syncthreads();
#pragma unroll 8
        for (int ks = 0; ks < 16; ++ks) {
            const int cwa = ((ks * 16 + kb * 4) ^ rswz);
            bf16x8 af0 = *(const bf16x8*)(As + lr * 256 + cwa);
            bf16x8 af1 = *(const bf16x8*)(As + (16 + lr) * 256 + cwa);
            bf16x8 b0 = *(const bf16x8*)(bsrc0 + c * 512 + ks * 32 + kb * 8);
            a00 = __builtin_amdgcn_mfma_f32_16x16x32_bf16(af0, b0, a00, 0, 0, 0);
            a10 = __builtin_amdgcn_mfma_f32_16x16x32_bf16(af1, b0, a10, 0, 0, 0);
            if (has2) {
                bf16x8 b1 = *(const bf16x8*)(bsrc1 + c * 512 + ks * 32 + kb * 8);
                a01 = __builtin_amdgcn_mfma_f32_16x16x32_bf16(af0, b1, a01, 0, 0, 0);
                a11 = __builtin_amdgcn_mfma_f32_16x16x32_bf16(af1, b1, a11, 0, 0, 0);
            }
        }
        __syncthreads();
    }

    // epilogue
#pragma unroll
    for (int nfi = 0; nfi < 2; ++nfi) {
        if (nfi == 1 && !has2) continue;
        const int cc = nfi ? c1 : c0;
        if (cc >= NC) continue;
        const float bias = fb[e * NC + cc];
        const f32x4 A0 = nfi ? a01 : a00;
        const f32x4 A1 = nfi ? a11 : a10;
#pragma unroll
        for (int m = 0; m < 2; ++m) {
            const f32x4 av = m ? A1 : A0;
#pragma unroll
            for (int j = 0; j < 4; ++j) {
                const int idx = m * 16 + kb * 4 + j;
                if (st * 32 + idx < cnt) {
                    outp[(size_t)sids[idx] * NC + cc] = spw[idx] * (av[j] + bias);
                }
            }
        }
    }
}

extern "C" void kernel_launch(void* const* d_in, const int* in_sizes, int n_in,
                              void* d_out, int out_size, void* d_ws, size_t ws_size,
                              hipStream_t stream) {
    const float* x   = (const float*)d_in[0];
    const float* rcw = (const float*)d_in[1];
    const float* rcb = (const float*)d_in[2];
    const float* rfw = (const float*)d_in[3];
    const float* rfb = (const float*)d_in[4];
    const float* ew1 = (const float*)d_in[5];
    const float* eb1 = (const float*)d_in[6];
    const float* ew2 = (const float*)d_in[7];
    const float* eb2 = (const float*)d_in[8];
    const float* efw = (const float*)d_in[9];
    const float* efb = (const float*)d_in[10];
    (void)in_sizes; (void)n_in; (void)out_size; (void)ws_size;

    float* out       = (float*)d_out;
    float* final_out = out;            // [512,100]
    float* probs_out = out + 51200;    // [512,4]
    float* aux_out   = out + 53248;    // [1]

    char* ws = (char*)d_ws;
    int*    sel  = (int*)ws;                                  // 512 ints
    float*  pw   = (float*)(ws + 2048);                       // 512 f32
    int*    ids  = (int*)(ws + 4096);                         // 512 ints
    int*    offs = (int*)(ws + 6144);                         // 8 ints
    uint*   h1b  = (uint*)(ws + 8192);                        // 512*4096 u32 = 8 MB (bf16 [16][16][32])
    uint*   h2b  = (uint*)(ws + 8192 + (size_t)8388608);      // 512*2048 u32 = 4 MB (bf16 [4096])
    ushort* fwb  = (ushort*)(ws + 8192 + 8388608 + 4194304);  // 400*4096 bf16 = 3.28 MB
    ushort* w2t  = (ushort*)(ws + 8192 + 8388608 + 4194304 + 3276800); // 73728 bf16

    cvt_fw_kernel<<<1600, 256, 0, stream>>>(efw, fwb);
    cvt_w2_kernel<<<288, 256, 0, stream>>>(ew2, w2t);
    router_kernel<<<512, 256, 0, stream>>>(x, rcw, rcb, rfw, rfb, probs_out, sel, pw);
    aux_kernel<<<1, 256, 0, stream>>>(probs_out, aux_out);
    scan_kernel<<<1, 512, 0, stream>>>(sel, ids, offs);
    expert1_kernel<<<512, 256, 0, stream>>>(x, ew1, eb1, sel, h1b);
    expert2_mfma_kernel<<<512, 256, 0, stream>>>(h1b, w2t, eb2, sel, (uint*)h2b);
    fc_mfma_kernel<<<dim3(16, 4), 256, 0, stream>>>((const ushort*)h2b, fwb, efb, ids, offs, pw, final_out);
}

// Round 4
// 90.702 us; speedup vs baseline: 2.3514x; 1.7957x over previous
//
#include <hip/hip_runtime.h>
#include <hip/hip_bf16.h>
#include <math.h>

#define BATCH 512
#define NC 100

typedef __attribute__((ext_vector_type(8))) short bf16x8;
typedef __attribute__((ext_vector_type(4))) float f32x4;

__device__ inline ushort f2bf(float f) {
    __hip_bfloat16 h = __float2bfloat16(f);
    return *reinterpret_cast<ushort*>(&h);
}

// ---------------- router: conv3x3(3->16)+relu -> mean -> fc(16->4) -> softmax -> top1 ----------------
__global__ __launch_bounds__(256) void router_kernel(
    const float* __restrict__ x,       // [B,3,32,32]
    const float* __restrict__ cw,      // [16,3,3,3]
    const float* __restrict__ cb,      // [16]
    const float* __restrict__ fcw,     // [4,16]
    const float* __restrict__ fcb,     // [4]
    float* __restrict__ probs_out,     // [B,4]
    int* __restrict__ sel,             // [B]
    float* __restrict__ pw)            // [B]
{
    __shared__ float xs[3][34][34];
    __shared__ float ws[16][27];
    __shared__ float bs[16];
    __shared__ float red[16][4];
    __shared__ float g[16];
    __shared__ float logits[4];

    const int b = blockIdx.x;
    const int tid = threadIdx.x;

    for (int i = tid; i < 3 * 34 * 34; i += 256) ((float*)xs)[i] = 0.f;
    for (int i = tid; i < 16 * 27; i += 256) ((float*)ws)[i] = cw[i];
    if (tid < 16) bs[tid] = cb[tid];
    __syncthreads();

    const float* xb = x + b * 3072;
    for (int i = tid; i < 3072; i += 256) {
        int c = i >> 10, r = (i >> 5) & 31, cc = i & 31;
        xs[c][r + 1][cc + 1] = xb[i];
    }
    __syncthreads();

    float acc[16];
#pragma unroll
    for (int o = 0; o < 16; ++o) acc[o] = 0.f;

    for (int k = 0; k < 4; ++k) {
        int p = tid + k * 256;
        int y = p >> 5, xx = p & 31;
        float v[27];
#pragma unroll
        for (int c = 0; c < 3; ++c)
#pragma unroll
            for (int ky = 0; ky < 3; ++ky)
#pragma unroll
                for (int kx = 0; kx < 3; ++kx)
                    v[c * 9 + ky * 3 + kx] = xs[c][y + ky][xx + kx];
#pragma unroll
        for (int o = 0; o < 16; ++o) {
            float s = bs[o];
#pragma unroll
            for (int j = 0; j < 27; ++j) s += v[j] * ws[o][j];
            acc[o] += fmaxf(s, 0.f);
        }
    }

    const int wid = tid >> 6;
#pragma unroll
    for (int o = 0; o < 16; ++o) {
        float s = acc[o];
#pragma unroll
        for (int off = 32; off > 0; off >>= 1) s += __shfl_down(s, off);
        if ((tid & 63) == 0) red[o][wid] = s;
    }
    __syncthreads();
    if (tid < 16) g[tid] = (red[tid][0] + red[tid][1] + red[tid][2] + red[tid][3]) * (1.f / 1024.f);
    __syncthreads();
    if (tid < 4) {
        float s = fcb[tid];
#pragma unroll
        for (int o = 0; o < 16; ++o) s += g[o] * fcw[tid * 16 + o];
        logits[tid] = s;
    }
    __syncthreads();
    if (tid == 0) {
        float m = logits[0];
        for (int e = 1; e < 4; ++e) m = fmaxf(m, logits[e]);
        float ex[4], s = 0.f;
        for (int e = 0; e < 4; ++e) { ex[e] = expf(logits[e] - m); s += ex[e]; }
        float inv = 1.f / s;
        int am = 0; float best = ex[0];
        for (int e = 1; e < 4; ++e) { if (ex[e] > best) { best = ex[e]; am = e; } }
        for (int e = 0; e < 4; ++e) probs_out[b * 4 + e] = ex[e] * inv;
        sel[b] = am;
        pw[b] = best * inv;
    }
}

// ---------------- aux loss ----------------
__global__ __launch_bounds__(256) void aux_kernel(const float* __restrict__ probs,
                                                  float* __restrict__ aux_out)
{
    __shared__ float red[256][4];
    const int tid = threadIdx.x;
    float s0 = 0, s1 = 0, s2 = 0, s3 = 0;
    for (int b = tid; b < BATCH; b += 256) {
        s0 += probs[b * 4 + 0]; s1 += probs[b * 4 + 1];
        s2 += probs[b * 4 + 2]; s3 += probs[b * 4 + 3];
    }
    red[tid][0] = s0; red[tid][1] = s1; red[tid][2] = s2; red[tid][3] = s3;
    __syncthreads();
    for (int off = 128; off > 0; off >>= 1) {
        if (tid < off) {
#pragma unroll
            for (int e = 0; e < 4; ++e) red[tid][e] += red[tid + off][e];
        }
        __syncthreads();
    }
    if (tid == 0) {
        float aux = 0;
        for (int e = 0; e < 4; ++e) {
            float mp = red[0][e] * (1.f / BATCH) - 0.25f;
            aux += mp * mp;
        }
        aux_out[0] = aux * 0.25f;
    }
}

// ---------------- scan: per-expert compaction via ballot ranking ----------------
__global__ __launch_bounds__(512) void scan_kernel(const int* __restrict__ sel,
                                                   int* __restrict__ ids,
                                                   int* __restrict__ offs)
{
    __shared__ int wcnt[4][8];     // [expert][wave]
    __shared__ int wbase[4][8];
    const int tid = threadIdx.x;
    const int wv = tid >> 6, lane = tid & 63;
    const int e = sel[tid];
    unsigned long long m[4];
#pragma unroll
    for (int k = 0; k < 4; ++k) m[k] = __ballot(e == k);
    if (lane == 0) {
#pragma unroll
        for (int k = 0; k < 4; ++k) wcnt[k][wv] = __popcll(m[k]);
    }
    __syncthreads();
    if (tid == 0) {
        int o = 0;
        for (int k = 0; k < 4; ++k) {
            offs[k] = o;
            for (int w = 0; w < 8; ++w) { wbase[k][w] = o; o += wcnt[k][w]; }
        }
        offs[4] = o;
    }
    __syncthreads();
    const unsigned long long below = (lane == 0) ? 0ull : (~0ull >> (64 - lane));
    const int rank = __popcll(m[e] & below);
    ids[wbase[e][wv] + rank] = tid;
}

// ---------------- convert fc weights to bf16 ----------------
__global__ __launch_bounds__(256) void cvt_fw_kernel(const float* __restrict__ fw,
                                                     ushort* __restrict__ fwb)
{
    const int i = (blockIdx.x * 256 + threadIdx.x) * 4;   // 1,638,400 divisible by 4
    float4 v = *(const float4*)(fw + i);
    ushort o[4];
    o[0] = f2bf(v.x); o[1] = f2bf(v.y); o[2] = f2bf(v.z); o[3] = f2bf(v.w);
    *(uint2*)(fwb + i) = *(uint2*)o;
}

// ---------------- convert conv2 weights: [4,64,32,3,3] f32 -> [4,9,64,32] bf16 ----------------
__global__ __launch_bounds__(256) void cvt_w2_kernel(const float* __restrict__ w2,
                                                     ushort* __restrict__ w2t)
{
    const int i = blockIdx.x * 256 + threadIdx.x;   // 288 blocks * 256 = 73728 exactly
    const int ic = i & 31;
    const int oc = (i >> 5) & 63;
    const int et = i >> 11;            // 0..35
    const int e = et / 9, t = et % 9;
    const float v = w2[((e * 64 + oc) * 32 + ic) * 9 + t];
    w2t[i] = f2bf(v);
}

// ---------------- expert conv1: conv3x3(3->32)+relu+maxpool2 -> h1b [b][16][16][32] bf16 ----------------
__global__ __launch_bounds__(256) void expert1_kernel(
    const float* __restrict__ x,
    const float* __restrict__ w1,   // [4,32,3,3,3]
    const float* __restrict__ b1,   // [4,32]
    const int* __restrict__ sel,
    uint* __restrict__ h1b)         // [B][16][16][32] bf16, as u32 words
{
    __shared__ float xs[3][34][34];
    __shared__ float ws[32][27];
    __shared__ float bs[32];
    __shared__ __align__(16) ushort outs[8192];   // [py][px][oc]
    const int b = blockIdx.x, tid = threadIdx.x;
    const int e = sel[b];

    for (int i = tid; i < 3 * 34 * 34; i += 256) ((float*)xs)[i] = 0.f;
    for (int i = tid; i < 32 * 27; i += 256) ((float*)ws)[i] = w1[e * 864 + i];
    if (tid < 32) bs[tid] = b1[e * 32 + tid];
    __syncthreads();

    const float* xb = x + b * 3072;
    for (int i = tid; i < 3072; i += 256) {
        int c = i >> 10, r = (i >> 5) & 31, cc = i & 31;
        xs[c][r + 1][cc + 1] = xb[i];
    }
    __syncthreads();

    const int oc = tid & 31;
    const float bias = bs[oc];
    for (int k = 0; k < 32; ++k) {
        const int px = ((tid >> 5) & 7) | ((k & 1) << 3);
        const int py = k >> 1;
        float s00 = 0.f, s01 = 0.f, s10 = 0.f, s11 = 0.f;
#pragma unroll
        for (int c = 0; c < 3; ++c) {
            float rv[4][4];
#pragma unroll
            for (int yy = 0; yy < 4; ++yy)
#pragma unroll
                for (int xx = 0; xx < 4; ++xx)
                    rv[yy][xx] = xs[c][2 * py + yy][2 * px + xx];
#pragma unroll
            for (int ky = 0; ky < 3; ++ky)
#pragma unroll
                for (int kx = 0; kx < 3; ++kx) {
                    const float w = ws[oc][c * 9 + ky * 3 + kx];
                    s00 += rv[ky][kx] * w;
                    s01 += rv[ky][kx + 1] * w;
                    s10 += rv[ky + 1][kx] * w;
                    s11 += rv[ky + 1][kx + 1] * w;
                }
        }
        float v = fmaxf(fmaxf(fmaxf(s00, s01), fmaxf(s10, s11)) + bias, 0.f);
        outs[(py * 16 + px) * 32 + oc] = f2bf(v);
    }
    __syncthreads();
    const uint* o32 = (const uint*)outs;
    uint* dst = h1b + (size_t)b * 4096;
    for (int i = tid; i < 4096; i += 256) dst[i] = o32[i];
}

// ---------------- expert conv2 via MFMA: 9 tap-GEMMs, pooled in-register ----------------
__global__ __launch_bounds__(256) void expert2_mfma_kernel(
    const uint* __restrict__ h1b,    // [B][16][16][32] bf16 (u32 words)
    const ushort* __restrict__ w2t,  // [4][9][64][32] bf16
    const float* __restrict__ b2,    // [4,64]
    const int* __restrict__ sel,
    uint* __restrict__ h2b)          // [B][4096] bf16 (u32 words): oc*64+py*8+px
{
    __shared__ __align__(16) ushort A_s[18 * 18 * 32];   // [y][x][ic] halo-padded, 20.7 KB
    __shared__ __align__(16) ushort W_s[9 * 64 * 32];    // [tap][oc][ic], 36.9 KB
    const int b = blockIdx.x, tid = threadIdx.x;
    const int e = sel[b];

    // halo zeros: 1088 u32 words
    uint* A32 = (uint*)A_s;
    for (int i = tid; i < 1088; i += 256) {
        int y, xx, w;
        if (i < 576) { y = (i >= 288) ? 17 : 0; int r2 = i % 288; xx = r2 >> 4; w = r2 & 15; }
        else { int j = i - 576; y = 1 + (j >> 5); xx = ((j >> 4) & 1) ? 17 : 0; w = j & 15; }
        A32[(y * 18 + xx) * 16 + w] = 0u;
    }
    // interior: 4096 u32 words
    const uint* hb = h1b + (size_t)b * 4096;
    for (int i = tid; i < 4096; i += 256) {
        int py = i >> 8, px = (i >> 4) & 15, w = i & 15;
        A32[((py + 1) * 18 + (px + 1)) * 16 + w] = hb[i];
    }
    // weights: 9216 u32 words
    uint* W32 = (uint*)W_s;
    const uint* wg = (const uint*)(w2t + (size_t)e * 18432);
    for (int i = tid; i < 9216; i += 256) W32[i] = wg[i];
    __syncthreads();

    const int wv = tid >> 6, lane = tid & 63;
    const int lr = lane & 15, kb = lane >> 4;

    f32x4 acc[4][4];
#pragma unroll
    for (int m = 0; m < 4; ++m)
#pragma unroll
        for (int n = 0; n < 4; ++n)
            acc[m][n] = (f32x4){0.f, 0.f, 0.f, 0.f};

#pragma unroll
    for (int t = 0; t < 9; ++t) {
        const int ky = t / 3, kx = t % 3;
        bf16x8 af[4], bfr[4];
#pragma unroll
        for (int m = 0; m < 4; ++m) {
            const int y = wv * 4 + m;
            af[m] = *(const bf16x8*)(A_s + ((y + ky) * 18 + (lr + kx)) * 32 + kb * 8);
        }
#pragma unroll
        for (int n = 0; n < 4; ++n)
            bfr[n] = *(const bf16x8*)(W_s + (t * 64 + n * 16 + lr) * 32 + kb * 8);
#pragma unroll
        for (int m = 0; m < 4; ++m)
#pragma unroll
            for (int n = 0; n < 4; ++n)
                acc[m][n] = __builtin_amdgcn_mfma_f32_16x16x32_bf16(af[m], bfr[n], acc[m][n], 0, 0, 0);
    }

    // epilogue: pool 2x2 in-register, +bias, relu, pack 2 bf16 -> u32
    const float bias = b2[e * 64 + lr];
#pragma unroll
    for (int q = 0; q < 2; ++q) {
        const int py = wv * 2 + q;
#pragma unroll
        for (int n = 0; n < 4; ++n) {
            const int oc = n * 16 + lr;
            const float bn = (n == 0) ? bias : b2[e * 64 + oc];
            const f32x4 ca = acc[2 * q][n];
            const f32x4 cb = acc[2 * q + 1][n];
            float p0 = fmaxf(fmaxf(ca[0], ca[1]), fmaxf(cb[0], cb[1]));
            float p1 = fmaxf(fmaxf(ca[2], ca[3]), fmaxf(cb[2], cb[3]));
            float r0 = fmaxf(p0 + bn, 0.f);
            float r1 = fmaxf(p1 + bn, 0.f);
            uint pk = (uint)f2bf(r0) | ((uint)f2bf(r1) << 16);
            h2b[(size_t)b * 2048 + oc * 32 + py * 4 + kb] = pk;
        }
    }
}

// ---------------- fc: K-split MFMA, partials to part[8][512][100] ----------------
// grid (mt 0..31, ks 0..7, e 0..3); block 448 = 7 waves, wave = one 16-class frag
__global__ __launch_bounds__(448) void fc_mfma_kernel(
    const ushort* __restrict__ h2b,   // [512,4096] bf16
    const ushort* __restrict__ fwb,   // [4,100,4096] bf16
    const int* __restrict__ ids,      // [512] grouped by expert
    const int* __restrict__ offs,     // [5]
    float* __restrict__ part)         // [8][512][100] f32
{
    const int mt = blockIdx.x, ks = blockIdx.y, e = blockIdx.z;
    const int off = offs[e], cnt = offs[e + 1] - off;
    if (mt * 16 >= cnt) return;

    const int tid = threadIdx.x;
    const int wv = tid >> 6, lane = tid & 63;
    const int lr = lane & 15, kb = lane >> 4;
    const int cls = wv * 16 + lr;                    // 0..111
    const int clsc = cls < NC ? cls : NC - 1;
    const int slot = mt * 16 + lr;
    const int sidx = ids[off + (slot < cnt ? slot : cnt - 1)];

    const ushort* ap = h2b + (size_t)sidx * 4096 + ks * 512 + kb * 8;
    const ushort* bp = fwb + (size_t)(e * NC + clsc) * 4096 + ks * 512 + kb * 8;

    f32x4 acc = {0.f, 0.f, 0.f, 0.f};
#pragma unroll
    for (int k = 0; k < 16; ++k) {
        bf16x8 a = *(const bf16x8*)(ap + k * 32);
        bf16x8 b = *(const bf16x8*)(bp + k * 32);
        acc = __builtin_amdgcn_mfma_f32_16x16x32_bf16(a, b, acc, 0, 0, 0);
    }

    if (cls < NC) {
#pragma unroll
        for (int j = 0; j < 4; ++j) {
            const int m = mt * 16 + kb * 4 + j;
            if (m < cnt) {
                const int sid = ids[off + m];
                part[((size_t)ks * 512 + sid) * NC + cls] = acc[j];
            }
        }
    }
}

// ---------------- fc reduce: sum 8 k-split partials, +bias, *pw ----------------
__global__ __launch_bounds__(256) void fc_reduce_kernel(
    const float* __restrict__ part,   // [8][512][100]
    const float* __restrict__ fb,     // [4,100]
    const int* __restrict__ sel,
    const float* __restrict__ pw,
    float* __restrict__ outp)         // [512,100]
{
    const int i = blockIdx.x * 256 + threadIdx.x;
    if (i >= BATCH * NC) return;
    const int s = i / NC, c = i - s * NC;
    float acc = 0.f;
#pragma unroll
    for (int k = 0; k < 8; ++k) acc += part[((size_t)k * 512 + s) * NC + c];
    outp[i] = pw[s] * (acc + fb[sel[s] * NC + c]);
}

extern "C" void kernel_launch(void* const* d_in, const int* in_sizes, int n_in,
                              void* d_out, int out_size, void* d_ws, size_t ws_size,
                              hipStream_t stream) {
    const float* x   = (const float*)d_in[0];
    const float* rcw = (const float*)d_in[1];
    const float* rcb = (const float*)d_in[2];
    const float* rfw = (const float*)d_in[3];
    const float* rfb = (const float*)d_in[4];
    const float* ew1 = (const float*)d_in[5];
    const float* eb1 = (const float*)d_in[6];
    const float* ew2 = (const float*)d_in[7];
    const float* eb2 = (const float*)d_in[8];
    const float* efw = (const float*)d_in[9];
    const float* efb = (const float*)d_in[10];
    (void)in_sizes; (void)n_in; (void)out_size; (void)ws_size;

    float* out       = (float*)d_out;
    float* final_out = out;            // [512,100]
    float* probs_out = out + 51200;    // [512,4]
    float* aux_out   = out + 53248;    // [1]

    char* ws = (char*)d_ws;
    int*    sel  = (int*)ws;                                  // 512 ints
    float*  pw   = (float*)(ws + 2048);                       // 512 f32
    int*    ids  = (int*)(ws + 4096);                         // 512 ints
    int*    offs = (int*)(ws + 6144);                         // 8 ints
    uint*   h1b  = (uint*)(ws + 8192);                        // 8 MB (bf16 [16][16][32])
    uint*   h2b  = (uint*)(ws + 8192 + (size_t)8388608);      // 4 MB (bf16 [4096])
    ushort* fwb  = (ushort*)(ws + 8192 + 8388608 + 4194304);  // 3.28 MB
    ushort* w2t  = (ushort*)(ws + 8192 + 8388608 + 4194304 + 3276800);          // 144 KB
    float*  part = (float*)(ws + 8192 + 8388608 + 4194304 + 3276800 + 147456);  // 1.64 MB

    cvt_fw_kernel<<<1600, 256, 0, stream>>>(efw, fwb);
    cvt_w2_kernel<<<288, 256, 0, stream>>>(ew2, w2t);
    router_kernel<<<512, 256, 0, stream>>>(x, rcw, rcb, rfw, rfb, probs_out, sel, pw);
    aux_kernel<<<1, 256, 0, stream>>>(probs_out, aux_out);
    scan_kernel<<<1, 512, 0, stream>>>(sel, ids, offs);
    expert1_kernel<<<512, 256, 0, stream>>>(x, ew1, eb1, sel, h1b);
    expert2_mfma_kernel<<<512, 256, 0, stream>>>(h1b, w2t, eb2, sel, (uint*)h2b);
    fc_mfma_kernel<<<dim3(32, 8, 4), 448, 0, stream>>>((const ushort*)h2b, fwb, ids, offs, part);
    fc_reduce_kernel<<<200, 256, 0, stream>>>(part, efb, sel, pw, final_out);
}

// Round 5
// 73.299 us; speedup vs baseline: 2.9097x; 1.2374x over previous
//
#include <hip/hip_runtime.h>
#include <hip/hip_bf16.h>
#include <math.h>

#define BATCH 512
#define NC 100

typedef __attribute__((ext_vector_type(8))) short bf16x8;
typedef __attribute__((ext_vector_type(4))) float f32x4;

__device__ inline ushort f2bf(float f) {
    __hip_bfloat16 h = __float2bfloat16(f);
    return *reinterpret_cast<ushort*>(&h);
}

// ---------------- router conv: conv3x3(3->16)+relu -> mean  => g[512][16] ----------------
// block 256 = 16 oc x 16 pixel-groups; thread owns one oc, weights in registers
__global__ __launch_bounds__(256) void router_conv_kernel(
    const float* __restrict__ x,       // [B,3,32,32]
    const float* __restrict__ cw,      // [16,3,3,3]
    const float* __restrict__ cb,      // [16]
    float* __restrict__ g_out)         // [B,16]
{
    __shared__ float xs[3][34][34];
    __shared__ float wsm[16][27];
    __shared__ float red[4][16];
    const int b = blockIdx.x, tid = threadIdx.x;

    for (int i = tid; i < 3 * 34 * 34; i += 256) ((float*)xs)[i] = 0.f;
    for (int i = tid; i < 432; i += 256) wsm[i / 27][i % 27] = cw[i];
    __syncthreads();

    const float* xb = x + b * 3072;
    for (int i = tid; i < 3072; i += 256) {
        int c = i >> 10, r = (i >> 5) & 31, cc = i & 31;
        xs[c][r + 1][cc + 1] = xb[i];
    }
    __syncthreads();

    const int oc = tid & 15, pg = tid >> 4;   // pg = output row-pair 0..15
    float w[27];
#pragma unroll
    for (int j = 0; j < 27; ++j) w[j] = wsm[oc][j];
    const float bias = cb[oc];

    float acc = 0.f;
    for (int bx = 0; bx < 16; ++bx) {
        float s00 = 0.f, s01 = 0.f, s10 = 0.f, s11 = 0.f;
#pragma unroll
        for (int c = 0; c < 3; ++c) {
            float rv[4][4];
#pragma unroll
            for (int yy = 0; yy < 4; ++yy)
#pragma unroll
                for (int xx = 0; xx < 4; ++xx)
                    rv[yy][xx] = xs[c][2 * pg + yy][2 * bx + xx];
#pragma unroll
            for (int ky = 0; ky < 3; ++ky)
#pragma unroll
                for (int kx = 0; kx < 3; ++kx) {
                    const float wv = w[c * 9 + ky * 3 + kx];
                    s00 += rv[ky][kx] * wv;
                    s01 += rv[ky][kx + 1] * wv;
                    s10 += rv[ky + 1][kx] * wv;
                    s11 += rv[ky + 1][kx + 1] * wv;
                }
        }
        acc += fmaxf(s00 + bias, 0.f) + fmaxf(s01 + bias, 0.f)
             + fmaxf(s10 + bias, 0.f) + fmaxf(s11 + bias, 0.f);
    }
    // reduce across pg: wave holds pg = 4w..4w+3 (lane = (pg&3)*16 + oc)
    acc += __shfl_down(acc, 32);
    acc += __shfl_down(acc, 16);
    if ((tid & 63) < 16) red[tid >> 6][oc] = acc;
    __syncthreads();
    if (tid < 16)
        g_out[b * 16 + tid] = (red[0][tid] + red[1][tid] + red[2][tid] + red[3][tid]) * (1.f / 1024.f);
}

// ---------------- router fc + softmax + top1 + aux: 1 block, 512 threads ----------------
__global__ __launch_bounds__(512) void router_fc_kernel(
    const float* __restrict__ g,       // [512,16]
    const float* __restrict__ fcw,     // [4,16]
    const float* __restrict__ fcb,     // [4]
    float* __restrict__ probs_out,     // [512,4]
    int* __restrict__ sel,             // [512]
    float* __restrict__ pw,            // [512]
    float* __restrict__ aux_out)       // [1]
{
    __shared__ float fw_s[64];
    __shared__ float fb_s[4];
    __shared__ float wred[8][4];
    const int tid = threadIdx.x;
    if (tid < 64) fw_s[tid] = fcw[tid];
    if (tid < 4) fb_s[tid] = fcb[tid];
    __syncthreads();

    const float4* gp = (const float4*)(g + tid * 16);
    const float4 g0 = gp[0], g1 = gp[1], g2 = gp[2], g3 = gp[3];

    float logits[4];
#pragma unroll
    for (int e = 0; e < 4; ++e) {
        const float* we = fw_s + e * 16;
        float s = fb_s[e];
        s += g0.x * we[0] + g0.y * we[1] + g0.z * we[2] + g0.w * we[3];
        s += g1.x * we[4] + g1.y * we[5] + g1.z * we[6] + g1.w * we[7];
        s += g2.x * we[8] + g2.y * we[9] + g2.z * we[10] + g2.w * we[11];
        s += g3.x * we[12] + g3.y * we[13] + g3.z * we[14] + g3.w * we[15];
        logits[e] = s;
    }
    float m = fmaxf(fmaxf(logits[0], logits[1]), fmaxf(logits[2], logits[3]));
    float ex[4], ssum = 0.f;
#pragma unroll
    for (int e = 0; e < 4; ++e) { ex[e] = __expf(logits[e] - m); ssum += ex[e]; }
    const float inv = 1.f / ssum;
    float p[4];
#pragma unroll
    for (int e = 0; e < 4; ++e) p[e] = ex[e] * inv;
    int am = 0; float best = p[0];
#pragma unroll
    for (int e = 1; e < 4; ++e) { if (p[e] > best) { best = p[e]; am = e; } }

    *(float4*)(probs_out + tid * 4) = make_float4(p[0], p[1], p[2], p[3]);
    sel[tid] = am;
    pw[tid] = best;

    // aux: deterministic tree-reduce of per-expert prob sums
    float s0 = p[0], s1 = p[1], s2 = p[2], s3 = p[3];
#pragma unroll
    for (int off = 32; off > 0; off >>= 1) {
        s0 += __shfl_down(s0, off);
        s1 += __shfl_down(s1, off);
        s2 += __shfl_down(s2, off);
        s3 += __shfl_down(s3, off);
    }
    const int wv = tid >> 6;
    if ((tid & 63) == 0) { wred[wv][0] = s0; wred[wv][1] = s1; wred[wv][2] = s2; wred[wv][3] = s3; }
    __syncthreads();
    if (tid == 0) {
        float aux = 0.f;
#pragma unroll
        for (int e = 0; e < 4; ++e) {
            float t = 0.f;
            for (int w = 0; w < 8; ++w) t += wred[w][e];
            float mp = t * (1.f / BATCH) - 0.25f;
            aux += mp * mp;
        }
        aux_out[0] = aux * 0.25f;
    }
}

// ---------------- scan: per-expert compaction via ballot ranking ----------------
__global__ __launch_bounds__(512) void scan_kernel(const int* __restrict__ sel,
                                                   int* __restrict__ ids,
                                                   int* __restrict__ offs)
{
    __shared__ int wcnt[4][8];
    __shared__ int wbase[4][8];
    const int tid = threadIdx.x;
    const int wv = tid >> 6, lane = tid & 63;
    const int e = sel[tid];
    unsigned long long m[4];
#pragma unroll
    for (int k = 0; k < 4; ++k) m[k] = __ballot(e == k);
    if (lane == 0) {
#pragma unroll
        for (int k = 0; k < 4; ++k) wcnt[k][wv] = __popcll(m[k]);
    }
    __syncthreads();
    if (tid == 0) {
        int o = 0;
        for (int k = 0; k < 4; ++k) {
            offs[k] = o;
            for (int w = 0; w < 8; ++w) { wbase[k][w] = o; o += wcnt[k][w]; }
        }
        offs[4] = o;
    }
    __syncthreads();
    const unsigned long long below = (lane == 0) ? 0ull : (~0ull >> (64 - lane));
    const int rank = __popcll(m[e] & below);
    ids[wbase[e][wv] + rank] = tid;
}

// ---------------- convert fc weights to bf16 ----------------
__global__ __launch_bounds__(256) void cvt_fw_kernel(const float* __restrict__ fw,
                                                     ushort* __restrict__ fwb)
{
    const int i = (blockIdx.x * 256 + threadIdx.x) * 4;
    float4 v = *(const float4*)(fw + i);
    ushort o[4];
    o[0] = f2bf(v.x); o[1] = f2bf(v.y); o[2] = f2bf(v.z); o[3] = f2bf(v.w);
    *(uint2*)(fwb + i) = *(uint2*)o;
}

// ---------------- convert conv2 weights: [4,64,32,3,3] f32 -> [4,9,64,32] bf16 ----------------
__global__ __launch_bounds__(256) void cvt_w2_kernel(const float* __restrict__ w2,
                                                     ushort* __restrict__ w2t)
{
    const int i = blockIdx.x * 256 + threadIdx.x;
    const int ic = i & 31;
    const int oc = (i >> 5) & 63;
    const int et = i >> 11;
    const int e = et / 9, t = et % 9;
    const float v = w2[((e * 64 + oc) * 32 + ic) * 9 + t];
    w2t[i] = f2bf(v);
}

// ---------------- expert conv1: conv3x3(3->32)+relu+maxpool2 -> h1b [b][16][16][32] bf16 ----------------
__global__ __launch_bounds__(256) void expert1_kernel(
    const float* __restrict__ x,
    const float* __restrict__ w1,   // [4,32,3,3,3]
    const float* __restrict__ b1,   // [4,32]
    const int* __restrict__ sel,
    uint* __restrict__ h1b)         // [B][16][16][32] bf16, as u32 words
{
    __shared__ float xs[3][34][34];
    __shared__ float ws[32][27];
    __shared__ float bs[32];
    __shared__ __align__(16) ushort outs[8192];   // [py][px][oc]
    const int b = blockIdx.x, tid = threadIdx.x;
    const int e = sel[b];

    for (int i = tid; i < 3 * 34 * 34; i += 256) ((float*)xs)[i] = 0.f;
    for (int i = tid; i < 32 * 27; i += 256) ((float*)ws)[i] = w1[e * 864 + i];
    if (tid < 32) bs[tid] = b1[e * 32 + tid];
    __syncthreads();

    const float* xb = x + b * 3072;
    for (int i = tid; i < 3072; i += 256) {
        int c = i >> 10, r = (i >> 5) & 31, cc = i & 31;
        xs[c][r + 1][cc + 1] = xb[i];
    }
    __syncthreads();

    const int oc = tid & 31;
    const float bias = bs[oc];
    for (int k = 0; k < 32; ++k) {
        const int px = ((tid >> 5) & 7) | ((k & 1) << 3);
        const int py = k >> 1;
        float s00 = 0.f, s01 = 0.f, s10 = 0.f, s11 = 0.f;
#pragma unroll
        for (int c = 0; c < 3; ++c) {
            float rv[4][4];
#pragma unroll
            for (int yy = 0; yy < 4; ++yy)
#pragma unroll
                for (int xx = 0; xx < 4; ++xx)
                    rv[yy][xx] = xs[c][2 * py + yy][2 * px + xx];
#pragma unroll
            for (int ky = 0; ky < 3; ++ky)
#pragma unroll
                for (int kx = 0; kx < 3; ++kx) {
                    const float w = ws[oc][c * 9 + ky * 3 + kx];
                    s00 += rv[ky][kx] * w;
                    s01 += rv[ky][kx + 1] * w;
                    s10 += rv[ky + 1][kx] * w;
                    s11 += rv[ky + 1][kx + 1] * w;
                }
        }
        float v = fmaxf(fmaxf(fmaxf(s00, s01), fmaxf(s10, s11)) + bias, 0.f);
        outs[(py * 16 + px) * 32 + oc] = f2bf(v);
    }
    __syncthreads();
    const uint* o32 = (const uint*)outs;
    uint* dst = h1b + (size_t)b * 4096;
    for (int i = tid; i < 4096; i += 256) dst[i] = o32[i];
}

// ---------------- expert conv2 via MFMA: 9 tap-GEMMs, pooled in-register ----------------
__global__ __launch_bounds__(256) void expert2_mfma_kernel(
    const uint* __restrict__ h1b,    // [B][16][16][32] bf16 (u32 words)
    const ushort* __restrict__ w2t,  // [4][9][64][32] bf16
    const float* __restrict__ b2,    // [4,64]
    const int* __restrict__ sel,
    uint* __restrict__ h2b)          // [B][4096] bf16 (u32 words): oc*64+py*8+px
{
    __shared__ __align__(16) ushort A_s[18 * 18 * 32];
    __shared__ __align__(16) ushort W_s[9 * 64 * 32];
    const int b = blockIdx.x, tid = threadIdx.x;
    const int e = sel[b];

    uint* A32 = (uint*)A_s;
    for (int i = tid; i < 1088; i += 256) {
        int y, xx, w;
        if (i < 576) { y = (i >= 288) ? 17 : 0; int r2 = i % 288; xx = r2 >> 4; w = r2 & 15; }
        else { int j = i - 576; y = 1 + (j >> 5); xx = ((j >> 4) & 1) ? 17 : 0; w = j & 15; }
        A32[(y * 18 + xx) * 16 + w] = 0u;
    }
    const uint* hb = h1b + (size_t)b * 4096;
    for (int i = tid; i < 4096; i += 256) {
        int py = i >> 8, px = (i >> 4) & 15, w = i & 15;
        A32[((py + 1) * 18 + (px + 1)) * 16 + w] = hb[i];
    }
    uint* W32 = (uint*)W_s;
    const uint* wg = (const uint*)(w2t + (size_t)e * 18432);
    for (int i = tid; i < 9216; i += 256) W32[i] = wg[i];
    __syncthreads();

    const int wv = tid >> 6, lane = tid & 63;
    const int lr = lane & 15, kb = lane >> 4;

    f32x4 acc[4][4];
#pragma unroll
    for (int m = 0; m < 4; ++m)
#pragma unroll
        for (int n = 0; n < 4; ++n)
            acc[m][n] = (f32x4){0.f, 0.f, 0.f, 0.f};

#pragma unroll
    for (int t = 0; t < 9; ++t) {
        const int ky = t / 3, kx = t % 3;
        bf16x8 af[4], bfr[4];
#pragma unroll
        for (int m = 0; m < 4; ++m) {
            const int y = wv * 4 + m;
            af[m] = *(const bf16x8*)(A_s + ((y + ky) * 18 + (lr + kx)) * 32 + kb * 8);
        }
#pragma unroll
        for (int n = 0; n < 4; ++n)
            bfr[n] = *(const bf16x8*)(W_s + (t * 64 + n * 16 + lr) * 32 + kb * 8);
#pragma unroll
        for (int m = 0; m < 4; ++m)
#pragma unroll
            for (int n = 0; n < 4; ++n)
                acc[m][n] = __builtin_amdgcn_mfma_f32_16x16x32_bf16(af[m], bfr[n], acc[m][n], 0, 0, 0);
    }

    const float bias = b2[e * 64 + lr];
#pragma unroll
    for (int q = 0; q < 2; ++q) {
        const int py = wv * 2 + q;
#pragma unroll
        for (int n = 0; n < 4; ++n) {
            const int oc = n * 16 + lr;
            const float bn = (n == 0) ? bias : b2[e * 64 + oc];
            const f32x4 ca = acc[2 * q][n];
            const f32x4 cb = acc[2 * q + 1][n];
            float p0 = fmaxf(fmaxf(ca[0], ca[1]), fmaxf(cb[0], cb[1]));
            float p1 = fmaxf(fmaxf(ca[2], ca[3]), fmaxf(cb[2], cb[3]));
            float r0 = fmaxf(p0 + bn, 0.f);
            float r1 = fmaxf(p1 + bn, 0.f);
            uint pk = (uint)f2bf(r0) | ((uint)f2bf(r1) << 16);
            h2b[(size_t)b * 2048 + oc * 32 + py * 4 + kb] = pk;
        }
    }
}

// ---------------- fc: K-split MFMA, partials to part[8][512][100] ----------------
__global__ __launch_bounds__(448) void fc_mfma_kernel(
    const ushort* __restrict__ h2b,   // [512,4096] bf16
    const ushort* __restrict__ fwb,   // [4,100,4096] bf16
    const int* __restrict__ ids,
    const int* __restrict__ offs,
    float* __restrict__ part)         // [8][512][100] f32
{
    const int mt = blockIdx.x, ks = blockIdx.y, e = blockIdx.z;
    const int off = offs[e], cnt = offs[e + 1] - off;
    if (mt * 16 >= cnt) return;

    const int tid = threadIdx.x;
    const int wv = tid >> 6, lane = tid & 63;
    const int lr = lane & 15, kb = lane >> 4;
    const int cls = wv * 16 + lr;
    const int clsc = cls < NC ? cls : NC - 1;
    const int slot = mt * 16 + lr;
    const int sidx = ids[off + (slot < cnt ? slot : cnt - 1)];

    const ushort* ap = h2b + (size_t)sidx * 4096 + ks * 512 + kb * 8;
    const ushort* bp = fwb + (size_t)(e * NC + clsc) * 4096 + ks * 512 + kb * 8;

    f32x4 acc = {0.f, 0.f, 0.f, 0.f};
#pragma unroll
    for (int k = 0; k < 16; ++k) {
        bf16x8 a = *(const bf16x8*)(ap + k * 32);
        bf16x8 b = *(const bf16x8*)(bp + k * 32);
        acc = __builtin_amdgcn_mfma_f32_16x16x32_bf16(a, b, acc, 0, 0, 0);
    }

    if (cls < NC) {
#pragma unroll
        for (int j = 0; j < 4; ++j) {
            const int m = mt * 16 + kb * 4 + j;
            if (m < cnt) {
                const int sid = ids[off + m];
                part[((size_t)ks * 512 + sid) * NC + cls] = acc[j];
            }
        }
    }
}

// ---------------- fc reduce: sum 8 k-split partials, +bias, *pw ----------------
__global__ __launch_bounds__(256) void fc_reduce_kernel(
    const float* __restrict__ part,
    const float* __restrict__ fb,
    const int* __restrict__ sel,
    const float* __restrict__ pw,
    float* __restrict__ outp)
{
    const int i = blockIdx.x * 256 + threadIdx.x;
    if (i >= BATCH * NC) return;
    const int s = i / NC, c = i - s * NC;
    float acc = 0.f;
#pragma unroll
    for (int k = 0; k < 8; ++k) acc += part[((size_t)k * 512 + s) * NC + c];
    outp[i] = pw[s] * (acc + fb[sel[s] * NC + c]);
}

extern "C" void kernel_launch(void* const* d_in, const int* in_sizes, int n_in,
                              void* d_out, int out_size, void* d_ws, size_t ws_size,
                              hipStream_t stream) {
    const float* x   = (const float*)d_in[0];
    const float* rcw = (const float*)d_in[1];
    const float* rcb = (const float*)d_in[2];
    const float* rfw = (const float*)d_in[3];
    const float* rfb = (const float*)d_in[4];
    const float* ew1 = (const float*)d_in[5];
    const float* eb1 = (const float*)d_in[6];
    const float* ew2 = (const float*)d_in[7];
    const float* eb2 = (const float*)d_in[8];
    const float* efw = (const float*)d_in[9];
    const float* efb = (const float*)d_in[10];
    (void)in_sizes; (void)n_in; (void)out_size; (void)ws_size;

    float* out       = (float*)d_out;
    float* final_out = out;            // [512,100]
    float* probs_out = out + 51200;    // [512,4]
    float* aux_out   = out + 53248;    // [1]

    char* ws = (char*)d_ws;
    int*    sel  = (int*)ws;                                  // 512 ints
    float*  pw   = (float*)(ws + 2048);                       // 512 f32
    int*    ids  = (int*)(ws + 4096);                         // 512 ints
    int*    offs = (int*)(ws + 6144);                         // 8 ints
    uint*   h1b  = (uint*)(ws + 8192);                        // 8 MB
    uint*   h2b  = (uint*)(ws + 8192 + (size_t)8388608);      // 4 MB
    ushort* fwb  = (ushort*)(ws + 8192 + 8388608 + 4194304);  // 3.28 MB
    ushort* w2t  = (ushort*)(ws + 8192 + 8388608 + 4194304 + 3276800);          // 144 KB
    float*  part = (float*)(ws + 8192 + 8388608 + 4194304 + 3276800 + 147456);  // 1.64 MB
    float*  g    = (float*)(ws + 8192 + 8388608 + 4194304 + 3276800 + 147456 + 1638400); // 32 KB

    cvt_fw_kernel<<<1600, 256, 0, stream>>>(efw, fwb);
    cvt_w2_kernel<<<288, 256, 0, stream>>>(ew2, w2t);
    router_conv_kernel<<<512, 256, 0, stream>>>(x, rcw, rcb, g);
    router_fc_kernel<<<1, 512, 0, stream>>>(g, rfw, rfb, probs_out, sel, pw, aux_out);
    scan_kernel<<<1, 512, 0, stream>>>(sel, ids, offs);
    expert1_kernel<<<512, 256, 0, stream>>>(x, ew1, eb1, sel, h1b);
    expert2_mfma_kernel<<<512, 256, 0, stream>>>(h1b, w2t, eb2, sel, (uint*)h2b);
    fc_mfma_kernel<<<dim3(32, 8, 4), 448, 0, stream>>>((const ushort*)h2b, fwb, ids, offs, part);
    fc_reduce_kernel<<<200, 256, 0, stream>>>(part, efb, sel, pw, final_out);
}

// Round 6
// 71.856 us; speedup vs baseline: 2.9681x; 1.0201x over previous
//
#include <hip/hip_runtime.h>
#include <hip/hip_bf16.h>
#include <math.h>

#define BATCH 512
#define NC 100

typedef __attribute__((ext_vector_type(8))) short bf16x8;
typedef __attribute__((ext_vector_type(4))) float f32x4;

__device__ inline ushort f2bf(float f) {
    __hip_bfloat16 h = __float2bfloat16(f);
    return *reinterpret_cast<ushort*>(&h);
}

// ---------------- cvt: fc weights f32->bf16 (blocks 0..1599), conv2 weights transpose (1600..1887) ----------------
__global__ __launch_bounds__(256) void cvt_all_kernel(const float* __restrict__ fw,
                                                      ushort* __restrict__ fwb,
                                                      const float* __restrict__ w2,
                                                      ushort* __restrict__ w2t)
{
    const int blk = blockIdx.x;
    if (blk < 1600) {
        const int i = (blk * 256 + threadIdx.x) * 4;   // 1,638,400 exact
        float4 v = *(const float4*)(fw + i);
        ushort o[4];
        o[0] = f2bf(v.x); o[1] = f2bf(v.y); o[2] = f2bf(v.z); o[3] = f2bf(v.w);
        *(uint2*)(fwb + i) = *(uint2*)o;
    } else {
        const int i = (blk - 1600) * 256 + threadIdx.x;  // 73,728 exact
        const int ic = i & 31;
        const int oc = (i >> 5) & 63;
        const int et = i >> 11;
        const int e = et / 9, t = et % 9;
        w2t[i] = f2bf(w2[((e * 64 + oc) * 32 + ic) * 9 + t]);
    }
}

// ---------------- fused per-sample: router -> top1 -> conv1 -> conv2(MFMA) -> h2b ----------------
__global__ __launch_bounds__(256) void fused_expert_kernel(
    const float* __restrict__ x,       // [B,3,32,32]
    const float* __restrict__ rcw,     // [16,3,3,3]
    const float* __restrict__ rcb,     // [16]
    const float* __restrict__ rfw,     // [4,16]
    const float* __restrict__ rfb,     // [4]
    const float* __restrict__ ew1,     // [4,32,3,3,3]
    const float* __restrict__ eb1,     // [4,32]
    const ushort* __restrict__ w2t,    // [4][9][64][32] bf16
    const float* __restrict__ eb2,     // [4,64]
    float* __restrict__ probs_out,     // [512,4]
    int* __restrict__ sel,             // [512]
    float* __restrict__ pw,            // [512]
    uint* __restrict__ h2b)            // [B][2048] u32 (bf16 pairs): oc*64+py*8+px
{
    __shared__ float xs[3][34][34];                      // 13.9 KB
    __shared__ float wsm[16][27];                        // router conv weights
    __shared__ float red[4][16];
    __shared__ float g_s[16];
    __shared__ int   sel_s;
    __shared__ float ws1[32][27];                        // conv1 weights (selected e)
    __shared__ float bs1[32];
    __shared__ __align__(16) ushort A_s[18 * 18 * 32];   // conv2 input, halo-padded, 20.7 KB
    __shared__ __align__(16) ushort W_s[9 * 64 * 32];    // conv2 weights, 36.9 KB

    const int b = blockIdx.x, tid = threadIdx.x;

    // ---- phase 0: zero A_s halo, zero xs border, stage xs + router weights ----
    uint* A32 = (uint*)A_s;
    for (int i = tid; i < 1088; i += 256) {
        int y, xx, w;
        if (i < 576) { y = (i >= 288) ? 17 : 0; int r2 = i % 288; xx = r2 >> 4; w = r2 & 15; }
        else { int j = i - 576; y = 1 + (j >> 5); xx = ((j >> 4) & 1) ? 17 : 0; w = j & 15; }
        A32[(y * 18 + xx) * 16 + w] = 0u;
    }
    for (int i = tid; i < 3 * 34 * 34; i += 256) ((float*)xs)[i] = 0.f;
    for (int i = tid; i < 432; i += 256) wsm[i / 27][i % 27] = rcw[i];
    __syncthreads();
    const float* xb = x + b * 3072;
    for (int i = tid; i < 3072; i += 256) {
        int c = i >> 10, r = (i >> 5) & 31, cc = i & 31;
        xs[c][r + 1][cc + 1] = xb[i];
    }
    __syncthreads();

    // ---- phase 1: router conv+relu+mean (oc = tid&15, row-pair pg = tid>>4) ----
    {
        const int oc = tid & 15, pg = tid >> 4;
        float w[27];
#pragma unroll
        for (int j = 0; j < 27; ++j) w[j] = wsm[oc][j];
        const float bias = rcb[oc];
        float acc = 0.f;
        for (int bx = 0; bx < 16; ++bx) {
            float s00 = 0.f, s01 = 0.f, s10 = 0.f, s11 = 0.f;
#pragma unroll
            for (int c = 0; c < 3; ++c) {
                float rv[4][4];
#pragma unroll
                for (int yy = 0; yy < 4; ++yy)
#pragma unroll
                    for (int xx = 0; xx < 4; ++xx)
                        rv[yy][xx] = xs[c][2 * pg + yy][2 * bx + xx];
#pragma unroll
                for (int ky = 0; ky < 3; ++ky)
#pragma unroll
                    for (int kx = 0; kx < 3; ++kx) {
                        const float wv = w[c * 9 + ky * 3 + kx];
                        s00 += rv[ky][kx] * wv;
                        s01 += rv[ky][kx + 1] * wv;
                        s10 += rv[ky + 1][kx] * wv;
                        s11 += rv[ky + 1][kx + 1] * wv;
                    }
            }
            acc += fmaxf(s00 + bias, 0.f) + fmaxf(s01 + bias, 0.f)
                 + fmaxf(s10 + bias, 0.f) + fmaxf(s11 + bias, 0.f);
        }
        acc += __shfl_down(acc, 32);
        acc += __shfl_down(acc, 16);
        if ((tid & 63) < 16) red[tid >> 6][oc] = acc;
    }
    __syncthreads();
    if (tid < 16) g_s[tid] = (red[0][tid] + red[1][tid] + red[2][tid] + red[3][tid]) * (1.f / 1024.f);
    __syncthreads();

    // ---- phase 2: fc(16->4) + softmax + top1 (thread 0) ----
    if (tid == 0) {
        float logits[4];
#pragma unroll
        for (int e = 0; e < 4; ++e) {
            float s = rfb[e];
#pragma unroll
            for (int o = 0; o < 16; ++o) s += g_s[o] * rfw[e * 16 + o];
            logits[e] = s;
        }
        float m = fmaxf(fmaxf(logits[0], logits[1]), fmaxf(logits[2], logits[3]));
        float ex[4], ssum = 0.f;
#pragma unroll
        for (int e = 0; e < 4; ++e) { ex[e] = __expf(logits[e] - m); ssum += ex[e]; }
        const float inv = 1.f / ssum;
        float p[4];
#pragma unroll
        for (int e = 0; e < 4; ++e) p[e] = ex[e] * inv;
        int am = 0; float best = p[0];
#pragma unroll
        for (int e = 1; e < 4; ++e) { if (p[e] > best) { best = p[e]; am = e; } }
        *(float4*)(probs_out + b * 4) = make_float4(p[0], p[1], p[2], p[3]);
        sel[b] = am;
        pw[b] = best;
        sel_s = am;
    }
    __syncthreads();
    const int e = sel_s;

    // ---- phase 3: stage conv1 + conv2 weights for expert e ----
    for (int i = tid; i < 864; i += 256) ((float*)ws1)[i] = ew1[e * 864 + i];
    if (tid < 32) bs1[tid] = eb1[e * 32 + tid];
    uint* W32 = (uint*)W_s;
    const uint* wg = (const uint*)(w2t + (size_t)e * 18432);
    for (int i = tid; i < 9216; i += 256) W32[i] = wg[i];
    __syncthreads();

    // ---- phase 4: conv1(3->32)+relu+pool -> A_s interior (bf16 [y][x][ic]) ----
    {
        const int oc = tid & 31;
        const float bias = bs1[oc];
        for (int k = 0; k < 32; ++k) {
            const int px = ((tid >> 5) & 7) | ((k & 1) << 3);
            const int py = k >> 1;
            float s00 = 0.f, s01 = 0.f, s10 = 0.f, s11 = 0.f;
#pragma unroll
            for (int c = 0; c < 3; ++c) {
                float rv[4][4];
#pragma unroll
                for (int yy = 0; yy < 4; ++yy)
#pragma unroll
                    for (int xx = 0; xx < 4; ++xx)
                        rv[yy][xx] = xs[c][2 * py + yy][2 * px + xx];
#pragma unroll
                for (int ky = 0; ky < 3; ++ky)
#pragma unroll
                    for (int kx = 0; kx < 3; ++kx) {
                        const float w = ws1[oc][c * 9 + ky * 3 + kx];
                        s00 += rv[ky][kx] * w;
                        s01 += rv[ky][kx + 1] * w;
                        s10 += rv[ky + 1][kx] * w;
                        s11 += rv[ky + 1][kx + 1] * w;
                    }
            }
            float v = fmaxf(fmaxf(fmaxf(s00, s01), fmaxf(s10, s11)) + bias, 0.f);
            A_s[((py + 1) * 18 + (px + 1)) * 32 + oc] = f2bf(v);
        }
    }
    __syncthreads();

    // ---- phase 5: conv2 via 9 tap-MFMAs + pool + relu -> h2b ----
    const int wv = tid >> 6, lane = tid & 63;
    const int lr = lane & 15, kb = lane >> 4;

    f32x4 acc[4][4];
#pragma unroll
    for (int m = 0; m < 4; ++m)
#pragma unroll
        for (int n = 0; n < 4; ++n)
            acc[m][n] = (f32x4){0.f, 0.f, 0.f, 0.f};

#pragma unroll
    for (int t = 0; t < 9; ++t) {
        const int ky = t / 3, kx = t % 3;
        bf16x8 af[4], bfr[4];
#pragma unroll
        for (int m = 0; m < 4; ++m) {
            const int y = wv * 4 + m;
            af[m] = *(const bf16x8*)(A_s + ((y + ky) * 18 + (lr + kx)) * 32 + kb * 8);
        }
#pragma unroll
        for (int n = 0; n < 4; ++n)
            bfr[n] = *(const bf16x8*)(W_s + (t * 64 + n * 16 + lr) * 32 + kb * 8);
#pragma unroll
        for (int m = 0; m < 4; ++m)
#pragma unroll
            for (int n = 0; n < 4; ++n)
                acc[m][n] = __builtin_amdgcn_mfma_f32_16x16x32_bf16(af[m], bfr[n], acc[m][n], 0, 0, 0);
    }

#pragma unroll
    for (int q = 0; q < 2; ++q) {
        const int py = wv * 2 + q;
#pragma unroll
        for (int n = 0; n < 4; ++n) {
            const int oc = n * 16 + lr;
            const float bn = eb2[e * 64 + oc];
            const f32x4 ca = acc[2 * q][n];
            const f32x4 cb = acc[2 * q + 1][n];
            float p0 = fmaxf(fmaxf(ca[0], ca[1]), fmaxf(cb[0], cb[1]));
            float p1 = fmaxf(fmaxf(ca[2], ca[3]), fmaxf(cb[2], cb[3]));
            float r0 = fmaxf(p0 + bn, 0.f);
            float r1 = fmaxf(p1 + bn, 0.f);
            uint pk = (uint)f2bf(r0) | ((uint)f2bf(r1) << 16);
            h2b[(size_t)b * 2048 + oc * 32 + py * 4 + kb] = pk;
        }
    }
}

// ---------------- scan + aux: per-expert compaction via ballot, aux tree-reduce ----------------
__global__ __launch_bounds__(512) void scan_aux_kernel(const int* __restrict__ sel,
                                                       const float* __restrict__ probs,
                                                       int* __restrict__ ids,
                                                       int* __restrict__ offs,
                                                       float* __restrict__ aux_out)
{
    __shared__ int wcnt[4][8];
    __shared__ int wbase[4][8];
    __shared__ float wred[8][4];
    const int tid = threadIdx.x;
    const int wv = tid >> 6, lane = tid & 63;
    const int e = sel[tid];
    unsigned long long m[4];
#pragma unroll
    for (int k = 0; k < 4; ++k) m[k] = __ballot(e == k);
    if (lane == 0) {
#pragma unroll
        for (int k = 0; k < 4; ++k) wcnt[k][wv] = __popcll(m[k]);
    }
    // aux partial sums
    float4 p = *(const float4*)(probs + tid * 4);
    float s0 = p.x, s1 = p.y, s2 = p.z, s3 = p.w;
#pragma unroll
    for (int off = 32; off > 0; off >>= 1) {
        s0 += __shfl_down(s0, off);
        s1 += __shfl_down(s1, off);
        s2 += __shfl_down(s2, off);
        s3 += __shfl_down(s3, off);
    }
    if (lane == 0) { wred[wv][0] = s0; wred[wv][1] = s1; wred[wv][2] = s2; wred[wv][3] = s3; }
    __syncthreads();
    if (tid == 0) {
        int o = 0;
        for (int k = 0; k < 4; ++k) {
            offs[k] = o;
            for (int w = 0; w < 8; ++w) { wbase[k][w] = o; o += wcnt[k][w]; }
        }
        offs[4] = o;
        float aux = 0.f;
#pragma unroll
        for (int k = 0; k < 4; ++k) {
            float t = 0.f;
            for (int w = 0; w < 8; ++w) t += wred[w][k];
            float mp = t * (1.f / BATCH) - 0.25f;
            aux += mp * mp;
        }
        aux_out[0] = aux * 0.25f;
    }
    __syncthreads();
    const unsigned long long below = (lane == 0) ? 0ull : (~0ull >> (64 - lane));
    const int rank = __popcll(m[e] & below);
    ids[wbase[e][wv] + rank] = tid;
}

// ---------------- fc: K-split MFMA, partials to part[8][512][100] ----------------
__global__ __launch_bounds__(448) void fc_mfma_kernel(
    const ushort* __restrict__ h2b,   // [512,4096] bf16
    const ushort* __restrict__ fwb,   // [4,100,4096] bf16
    const int* __restrict__ ids,
    const int* __restrict__ offs,
    float* __restrict__ part)         // [8][512][100] f32
{
    const int mt = blockIdx.x, ks = blockIdx.y, e = blockIdx.z;
    const int off = offs[e], cnt = offs[e + 1] - off;
    if (mt * 16 >= cnt) return;

    const int tid = threadIdx.x;
    const int wv = tid >> 6, lane = tid & 63;
    const int lr = lane & 15, kb = lane >> 4;
    const int cls = wv * 16 + lr;
    const int clsc = cls < NC ? cls : NC - 1;
    const int slot = mt * 16 + lr;
    const int sidx = ids[off + (slot < cnt ? slot : cnt - 1)];

    const ushort* ap = h2b + (size_t)sidx * 4096 + ks * 512 + kb * 8;
    const ushort* bp = fwb + (size_t)(e * NC + clsc) * 4096 + ks * 512 + kb * 8;

    f32x4 acc = {0.f, 0.f, 0.f, 0.f};
#pragma unroll
    for (int k = 0; k < 16; ++k) {
        bf16x8 a = *(const bf16x8*)(ap + k * 32);
        bf16x8 b = *(const bf16x8*)(bp + k * 32);
        acc = __builtin_amdgcn_mfma_f32_16x16x32_bf16(a, b, acc, 0, 0, 0);
    }

    if (cls < NC) {
#pragma unroll
        for (int j = 0; j < 4; ++j) {
            const int m = mt * 16 + kb * 4 + j;
            if (m < cnt) {
                const int sid = ids[off + m];
                part[((size_t)ks * 512 + sid) * NC + cls] = acc[j];
            }
        }
    }
}

// ---------------- fc reduce: sum 8 k-split partials, +bias, *pw ----------------
__global__ __launch_bounds__(256) void fc_reduce_kernel(
    const float* __restrict__ part,
    const float* __restrict__ fb,
    const int* __restrict__ sel,
    const float* __restrict__ pw,
    float* __restrict__ outp)
{
    const int i = blockIdx.x * 256 + threadIdx.x;
    if (i >= BATCH * NC) return;
    const int s = i / NC, c = i - s * NC;
    float acc = 0.f;
#pragma unroll
    for (int k = 0; k < 8; ++k) acc += part[((size_t)k * 512 + s) * NC + c];
    outp[i] = pw[s] * (acc + fb[sel[s] * NC + c]);
}

extern "C" void kernel_launch(void* const* d_in, const int* in_sizes, int n_in,
                              void* d_out, int out_size, void* d_ws, size_t ws_size,
                              hipStream_t stream) {
    const float* x   = (const float*)d_in[0];
    const float* rcw = (const float*)d_in[1];
    const float* rcb = (const float*)d_in[2];
    const float* rfw = (const float*)d_in[3];
    const float* rfb = (const float*)d_in[4];
    const float* ew1 = (const float*)d_in[5];
    const float* eb1 = (const float*)d_in[6];
    const float* ew2 = (const float*)d_in[7];
    const float* eb2 = (const float*)d_in[8];
    const float* efw = (const float*)d_in[9];
    const float* efb = (const float*)d_in[10];
    (void)in_sizes; (void)n_in; (void)out_size; (void)ws_size;

    float* out       = (float*)d_out;
    float* final_out = out;            // [512,100]
    float* probs_out = out + 51200;    // [512,4]
    float* aux_out   = out + 53248;    // [1]

    char* ws = (char*)d_ws;
    int*    sel  = (int*)ws;                                  // 512 ints
    float*  pw   = (float*)(ws + 2048);                       // 512 f32
    int*    ids  = (int*)(ws + 4096);                         // 512 ints
    int*    offs = (int*)(ws + 6144);                         // 8 ints
    uint*   h2b  = (uint*)(ws + 8192);                        // 4 MB (bf16 [512][4096])
    ushort* fwb  = (ushort*)(ws + 8192 + 4194304);            // 3.28 MB
    ushort* w2t  = (ushort*)(ws + 8192 + 4194304 + 3276800);  // 144 KB
    float*  part = (float*)(ws + 8192 + 4194304 + 3276800 + 147456);  // 1.64 MB

    cvt_all_kernel<<<1888, 256, 0, stream>>>(efw, fwb, ew2, w2t);
    fused_expert_kernel<<<512, 256, 0, stream>>>(x, rcw, rcb, rfw, rfb, ew1, eb1,
                                                 w2t, eb2, probs_out, sel, pw, h2b);
    scan_aux_kernel<<<1, 512, 0, stream>>>(sel, probs_out, ids, offs, aux_out);
    fc_mfma_kernel<<<dim3(32, 8, 4), 448, 0, stream>>>((const ushort*)h2b, fwb, ids, offs, part);
    fc_reduce_kernel<<<200, 256, 0, stream>>>(part, efb, sel, pw, final_out);
}